// Round 1
// baseline (3556.135 us; speedup 1.0000x reference)
//
#include <hip/hip_runtime.h>
#include <hip/hip_bf16.h>
#include <cstdint>

#define N_NODES 50000
#define N_EDGES 800000
#define N_GRAPHS 1024
#define NODE_IN 128
#define HID 300
#define DEPTH 5
#define READOUT 1024

// ---------------------------------------------------------------- CSR build
__global__ void hist_kernel(const int* __restrict__ dst, int* __restrict__ cnt, int n) {
    int i = blockIdx.x * blockDim.x + threadIdx.x;
    if (i < n) atomicAdd(&cnt[dst[i]], 1);
}

// single-block exclusive scan over n counters -> offs[n+1], copy to cursor
__global__ __launch_bounds__(1024)
void scan_kernel(const int* __restrict__ cnt, int* __restrict__ offs,
                 int* __restrict__ cursor, int n) {
    __shared__ int buf[1024];
    __shared__ int carry;
    if (threadIdx.x == 0) carry = 0;
    __syncthreads();
    for (int base = 0; base < n; base += 1024) {
        int i = base + (int)threadIdx.x;
        int v = (i < n) ? cnt[i] : 0;
        buf[threadIdx.x] = v;
        __syncthreads();
        // Hillis-Steele inclusive scan
        for (int off = 1; off < 1024; off <<= 1) {
            int t = (threadIdx.x >= (unsigned)off) ? buf[threadIdx.x - off] : 0;
            __syncthreads();
            buf[threadIdx.x] += t;
            __syncthreads();
        }
        int incl = buf[threadIdx.x];
        int excl = incl - v + carry;
        if (i < n) { offs[i] = excl; cursor[i] = excl; }
        __syncthreads();
        if (threadIdx.x == 1023) carry += buf[1023];
        __syncthreads();
    }
    if (threadIdx.x == 0) offs[n] = carry;
}

__global__ void scatter_kernel(const int* __restrict__ src, const int* __restrict__ dst,
                               int* __restrict__ cursor, int* __restrict__ csr, int n) {
    int i = blockIdx.x * blockDim.x + threadIdx.x;
    if (i < n) {
        int p = atomicAdd(&cursor[dst[i]], 1);
        csr[p] = src[i];
    }
}

// ---------------------------------------------------------------- aggregation
// agg[node] = h[node] + sum_{e: dst==node} h[src[e]]
// one wave (64 lanes) per node; 300 feats -> 5 slots per lane
__global__ __launch_bounds__(256)
void aggregate_kernel(const float* __restrict__ h, const int* __restrict__ offs,
                      const int* __restrict__ csr, float* __restrict__ out) {
    int wave = (int)((blockIdx.x * blockDim.x + threadIdx.x) >> 6);
    int lane = threadIdx.x & 63;
    if (wave >= N_NODES) return;
    const float* self = h + (size_t)wave * HID;
    float acc[5];
#pragma unroll
    for (int j = 0; j < 5; ++j) {
        int f = lane + j * 64;
        acc[j] = (f < HID) ? self[f] : 0.f;
    }
    int s = offs[wave], e = offs[wave + 1];
    for (int k = s; k < e; ++k) {
        const float* row = h + (size_t)csr[k] * HID;
#pragma unroll
        for (int j = 0; j < 5; ++j) {
            int f = lane + j * 64;
            if (f < HID) acc[j] += row[f];
        }
    }
    float* o = out + (size_t)wave * HID;
#pragma unroll
    for (int j = 0; j < 5; ++j) {
        int f = lane + j * 64;
        if (f < HID) o[f] = acc[j];
    }
}

// ---------------------------------------------------------------- GEMM (fp32)
// C[M,N] = act(A[M,K] * B[K,N] + bias)   act: 0=none 1=relu 2=prelu
#define BMT 64
#define BNT 64
#define BKT 16
__global__ __launch_bounds__(256)
void gemm_bias_act(const float* __restrict__ A, const float* __restrict__ B,
                   const float* __restrict__ bias, float* __restrict__ C,
                   int M, int N, int K, int act, const float* __restrict__ prelu) {
    __shared__ float As[BKT][BMT + 1];
    __shared__ float Bs[BKT][BNT + 1];
    int tid = threadIdx.x;
    int tx = tid & 15;   // N dir
    int ty = tid >> 4;   // M dir
    int block_m = blockIdx.y * BMT;
    int block_n = blockIdx.x * BNT;

    float acc[4][4] = {{0.f}};
    int a_m = tid >> 2;           // 0..63
    int a_k = (tid & 3) * 4;      // 0,4,8,12
    int b_k = tid >> 4;           // 0..15
    int b_n = (tid & 15) * 4;     // 0..60

    for (int k0 = 0; k0 < K; k0 += BKT) {
#pragma unroll
        for (int u = 0; u < 4; ++u) {
            int k = k0 + a_k + u;
            int m = block_m + a_m;
            As[a_k + u][a_m] = (m < M && k < K) ? A[(size_t)m * K + k] : 0.f;
        }
#pragma unroll
        for (int u = 0; u < 4; ++u) {
            int k = k0 + b_k;
            int n = block_n + b_n + u;
            Bs[b_k][b_n + u] = (k < K && n < N) ? B[(size_t)k * N + n] : 0.f;
        }
        __syncthreads();
#pragma unroll
        for (int kk = 0; kk < BKT; ++kk) {
            float a[4], b[4];
#pragma unroll
            for (int i = 0; i < 4; ++i) a[i] = As[kk][ty * 4 + i];
#pragma unroll
            for (int j = 0; j < 4; ++j) b[j] = Bs[kk][tx * 4 + j];
#pragma unroll
            for (int i = 0; i < 4; ++i)
#pragma unroll
                for (int j = 0; j < 4; ++j) acc[i][j] += a[i] * b[j];
        }
        __syncthreads();
    }
    float aslope = (act == 2) ? prelu[0] : 0.f;
#pragma unroll
    for (int i = 0; i < 4; ++i) {
        int m = block_m + ty * 4 + i;
        if (m >= M) continue;
#pragma unroll
        for (int j = 0; j < 4; ++j) {
            int n = block_n + tx * 4 + j;
            if (n >= N) continue;
            float v = acc[i][j] + bias[n];
            if (act == 1) v = fmaxf(v, 0.f);
            else if (act == 2) v = (v >= 0.f) ? v : aslope * v;
            C[(size_t)m * N + n] = v;
        }
    }
}

// ---------------------------------------------------------------- pooling
__global__ void pool_kernel(const float* __restrict__ h, const int* __restrict__ batch,
                            float* __restrict__ pooled) {
    int idx = blockIdx.x * blockDim.x + threadIdx.x;
    if (idx >= N_NODES * HID) return;
    int node = idx / HID;
    int f = idx - node * HID;
    atomicAdd(&pooled[(size_t)batch[node] * HID + f], h[idx]);
}

// ---------------------------------------------------------------- launch
extern "C" void kernel_launch(void* const* d_in, const int* in_sizes, int n_in,
                              void* d_out, int out_size, void* d_ws, size_t ws_size,
                              hipStream_t stream) {
    const float* x      = (const float*)d_in[0];
    const int*   eidx   = (const int*)d_in[1];
    const int*   batch  = (const int*)d_in[2];
    const float* W_proj = (const float*)d_in[3];
    const float* b_proj = (const float*)d_in[4];
    const float* W1     = (const float*)d_in[5];
    const float* b1     = (const float*)d_in[6];
    const float* W2     = (const float*)d_in[7];
    const float* b2     = (const float*)d_in[8];
    const float* W_sp   = (const float*)d_in[9];
    const float* b_sp   = (const float*)d_in[10];
    const float* prelu  = (const float*)d_in[11];

    const int* src = eidx;
    const int* dst = eidx + N_EDGES;

    // workspace layout
    float* hA     = (float*)d_ws;                       // 15,000,000 f
    float* hB     = hA + (size_t)N_NODES * HID;         // 15,000,000 f
    float* pooled = hB + (size_t)N_NODES * HID;         // 307,200 f
    int*   cnt    = (int*)(pooled + (size_t)N_GRAPHS * HID); // 50,000 i
    int*   offs   = cnt + N_NODES;                      // 50,001 i
    int*   cursor = offs + N_NODES + 1;                 // 50,000 i
    int*   csr    = cursor + N_NODES;                   // 800,000 i
    size_t needed = ((size_t)(csr + N_EDGES) - (size_t)d_ws);
    if (ws_size < needed) return;  // insufficient scratch

    // --- CSR by dst (rebuilt every call; deterministic work) ---
    hipMemsetAsync(cnt, 0, N_NODES * sizeof(int), stream);
    hist_kernel<<<(N_EDGES + 255) / 256, 256, 0, stream>>>(dst, cnt, N_EDGES);
    scan_kernel<<<1, 1024, 0, stream>>>(cnt, offs, cursor, N_NODES);
    scatter_kernel<<<(N_EDGES + 255) / 256, 256, 0, stream>>>(src, dst, cursor, csr, N_EDGES);

    // --- projection: h = relu(x @ W_proj + b_proj) ---
    {
        dim3 grid((HID + BNT - 1) / BNT, (N_NODES + BMT - 1) / BMT);
        gemm_bias_act<<<grid, 256, 0, stream>>>(x, W_proj, b_proj, hA,
                                                N_NODES, HID, NODE_IN, 1, nullptr);
    }

    float* cur = hA;
    float* alt = hB;
    dim3 ggrid((HID + BNT - 1) / BNT, (N_NODES + BMT - 1) / BMT);
    for (int i = 0; i < DEPTH; ++i) {
        // agg = cur + A*cur  -> alt
        aggregate_kernel<<<(N_NODES * 64 + 255) / 256, 256, 0, stream>>>(cur, offs, csr, alt);
        // t = relu(agg @ W1_i + b1_i) -> cur
        gemm_bias_act<<<ggrid, 256, 0, stream>>>(alt, W1 + (size_t)i * HID * HID,
                                                 b1 + (size_t)i * HID, cur,
                                                 N_NODES, HID, HID, 1, nullptr);
        // h = (relu?)(t @ W2_i + b2_i) -> alt
        gemm_bias_act<<<ggrid, 256, 0, stream>>>(cur, W2 + (size_t)i * HID * HID,
                                                 b2 + (size_t)i * HID, alt,
                                                 N_NODES, HID, HID, (i < DEPTH - 1) ? 1 : 0,
                                                 nullptr);
        float* tmp = cur; cur = alt; alt = tmp;
    }

    // --- global_add_pool ---
    hipMemsetAsync(pooled, 0, (size_t)N_GRAPHS * HID * sizeof(float), stream);
    pool_kernel<<<(N_NODES * HID + 255) / 256, 256, 0, stream>>>(cur, batch, pooled);

    // --- readout: out = prelu(pooled @ W_sp + b_sp) ---
    {
        dim3 grid((READOUT + BNT - 1) / BNT, (N_GRAPHS + BMT - 1) / BMT);
        gemm_bias_act<<<grid, 256, 0, stream>>>(pooled, W_sp, b_sp, (float*)d_out,
                                                N_GRAPHS, READOUT, HID, 2, prelu);
    }
}

// Round 2
// 2900.197 us; speedup vs baseline: 1.2262x; 1.2262x over previous
//
#include <hip/hip_runtime.h>
#include <hip/hip_bf16.h>
#include <cstdint>

#define N_NODES 50000
#define N_EDGES 800000
#define N_GRAPHS 1024
#define NODE_IN 128
#define HID 300
#define DEPTH 5
#define READOUT 1024

typedef _Float16 f16;
typedef f16 f16x4 __attribute__((ext_vector_type(4)));
typedef f16 f16x8 __attribute__((ext_vector_type(8)));
typedef float f32x4 __attribute__((ext_vector_type(4)));

// ---------------------------------------------------------------- CSR build
__global__ void hist_kernel(const int* __restrict__ dst, int* __restrict__ cnt, int n) {
    int i = blockIdx.x * blockDim.x + threadIdx.x;
    if (i < n) atomicAdd(&cnt[dst[i]], 1);
}

__global__ __launch_bounds__(1024)
void scan_kernel(const int* __restrict__ cnt, int* __restrict__ offs,
                 int* __restrict__ cursor, int n) {
    __shared__ int buf[1024];
    __shared__ int carry;
    if (threadIdx.x == 0) carry = 0;
    __syncthreads();
    for (int base = 0; base < n; base += 1024) {
        int i = base + (int)threadIdx.x;
        int v = (i < n) ? cnt[i] : 0;
        buf[threadIdx.x] = v;
        __syncthreads();
        for (int off = 1; off < 1024; off <<= 1) {
            int t = (threadIdx.x >= (unsigned)off) ? buf[threadIdx.x - off] : 0;
            __syncthreads();
            buf[threadIdx.x] += t;
            __syncthreads();
        }
        int incl = buf[threadIdx.x];
        int excl = incl - v + carry;
        if (i < n) { offs[i] = excl; cursor[i] = excl; }
        __syncthreads();
        if (threadIdx.x == 1023) carry += buf[1023];
        __syncthreads();
    }
    if (threadIdx.x == 0) offs[n] = carry;
}

__global__ void scatter_kernel(const int* __restrict__ src, const int* __restrict__ dst,
                               int* __restrict__ cursor, int* __restrict__ csr, int n) {
    int i = blockIdx.x * blockDim.x + threadIdx.x;
    if (i < n) {
        int p = atomicAdd(&cursor[dst[i]], 1);
        csr[p] = src[i];
    }
}

// ---------------------------------------------------------------- aggregation
__global__ __launch_bounds__(256)
void aggregate_kernel(const float* __restrict__ h, const int* __restrict__ offs,
                      const int* __restrict__ csr, float* __restrict__ out) {
    int wave = (int)((blockIdx.x * blockDim.x + threadIdx.x) >> 6);
    int lane = threadIdx.x & 63;
    if (wave >= N_NODES) return;
    const float* self = h + (size_t)wave * HID;
    float acc[5];
#pragma unroll
    for (int j = 0; j < 5; ++j) {
        int f = lane + j * 64;
        acc[j] = (f < HID) ? self[f] : 0.f;
    }
    int s = offs[wave], e = offs[wave + 1];
    for (int k = s; k < e; ++k) {
        const float* row = h + (size_t)csr[k] * HID;
#pragma unroll
        for (int j = 0; j < 5; ++j) {
            int f = lane + j * 64;
            if (f < HID) acc[j] += row[f];
        }
    }
    float* o = out + (size_t)wave * HID;
#pragma unroll
    for (int j = 0; j < 5; ++j) {
        int f = lane + j * 64;
        if (f < HID) o[f] = acc[j];
    }
}

// ---------------------------------------------------------------- amax + scale
__global__ void amax_kernel(const float* __restrict__ A, int n, unsigned* __restrict__ slot) {
    float m = 0.f;
    for (int i = blockIdx.x * blockDim.x + threadIdx.x; i < n; i += gridDim.x * blockDim.x)
        m = fmaxf(m, fabsf(A[i]));
#pragma unroll
    for (int off = 32; off; off >>= 1) m = fmaxf(m, __shfl_xor(m, off));
    if ((threadIdx.x & 63) == 0) atomicMax(slot, __float_as_uint(m));
}

// sc[0]=scale (pow2), sc[1]=1/scale ; scaled amax lands in (2^11, 2^12]
__global__ void scale_from_amax(const unsigned* __restrict__ slot, float* __restrict__ sc) {
    float amax = __uint_as_float(*slot);
    float s = 1.f;
    if (amax > 0.f) s = exp2f(floorf(12.f - log2f(amax)));
    sc[0] = s;
    sc[1] = 1.f / s;
}

// ---------------------------------------------------------------- weight pre-split
// W [K][N] fp32 (row-major, N-contig) -> hi/lo [NP][KP] f16 (transposed, zero-padded)
__global__ void split_weight(const float* __restrict__ W, int K, int N, int KP,
                             f16* __restrict__ hi, f16* __restrict__ lo) {
    int n = blockIdx.x;  // 0..NP-1
    for (int k = threadIdx.x; k < KP; k += blockDim.x) {
        float v = 0.f;
        if (k < K && n < N) v = W[(size_t)k * N + n];
        f16 h = (f16)v;
        hi[(size_t)n * KP + k] = h;
        lo[(size_t)n * KP + k] = (f16)(v - (float)h);
    }
}

// ---------------------------------------------------------------- split-f16 MFMA GEMM
// C[M,N] = act( (A*s @ (Bhi+Blo)) * (1/s) + bias ),  A fp32, B pre-split f16
// block: 256 thr = 4 waves (2x2), tile 128x64, BK=32
#define GBM 128
#define GBN 64
#define GBK 32
__global__ __launch_bounds__(256)
void gemm_split_f16(const float* __restrict__ A, int lda, int M, int K,
                    const f16* __restrict__ BtH, const f16* __restrict__ BtL, int KP,
                    const float* __restrict__ bias, float* __restrict__ C, int N, int ldc,
                    const float* __restrict__ scv, int act, const float* __restrict__ prelu) {
    __shared__ __align__(16) f16 AsH[GBM * GBK];
    __shared__ __align__(16) f16 AsL[GBM * GBK];
    __shared__ __align__(16) f16 BsH[GBN * GBK];
    __shared__ __align__(16) f16 BsL[GBN * GBK];

    int tid = threadIdx.x;
    int bm = blockIdx.y * GBM;
    int bn = blockIdx.x * GBN;
    int wid = tid >> 6, lane = tid & 63;
    int wm = wid >> 1, wn = wid & 1;
    int lr = lane & 15, lk = lane >> 4;  // fragment row/col, k-chunk

    float a_scale = scv[0];

    f32x4 acc[4][2];
#pragma unroll
    for (int i = 0; i < 4; ++i)
#pragma unroll
        for (int j = 0; j < 2; ++j) acc[i][j] = (f32x4)0.f;

    int aq = tid & 7;    // float4 chunk within row (k-offset aq*4)
    int ar = tid >> 3;   // row 0..31 (+32*pass)
    int bq = tid & 3;    // 16B chunk (8 f16)
    int bnr = tid >> 2;  // 0..63

    for (int k0 = 0; k0 < KP; k0 += GBK) {
        // ---- stage A: fp32 -> scaled hi/lo f16, swizzled LDS
#pragma unroll
        for (int p = 0; p < 4; ++p) {
            int r = ar + p * 32;
            int m = bm + r;
            int k = k0 + aq * 4;
            float4 v = make_float4(0.f, 0.f, 0.f, 0.f);
            if (m < M) {
                if (k + 3 < K) v = *(const float4*)&A[(size_t)m * lda + k];
                else {
                    if (k + 0 < K) v.x = A[(size_t)m * lda + k + 0];
                    if (k + 1 < K) v.y = A[(size_t)m * lda + k + 1];
                    if (k + 2 < K) v.z = A[(size_t)m * lda + k + 2];
                    if (k + 3 < K) v.w = A[(size_t)m * lda + k + 3];
                }
            }
            v.x *= a_scale; v.y *= a_scale; v.z *= a_scale; v.w *= a_scale;
            f16x4 h, l;
            h[0] = (f16)v.x; l[0] = (f16)(v.x - (float)h[0]);
            h[1] = (f16)v.y; l[1] = (f16)(v.y - (float)h[1]);
            h[2] = (f16)v.z; l[2] = (f16)(v.z - (float)h[2]);
            h[3] = (f16)v.w; l[3] = (f16)(v.w - (float)h[3]);
            int cs = (aq >> 1) ^ ((r >> 1) & 3);
            int idx = r * GBK + cs * 8 + (aq & 1) * 4;
            *(f16x4*)&AsH[idx] = h;
            *(f16x4*)&AsL[idx] = l;
        }
        // ---- stage B: copy pre-split rows (always valid: Bt padded to NP x KP)
        {
            int n = bn + bnr;
            int cs = bq ^ ((bnr >> 1) & 3);
            size_t gb = (size_t)n * KP + k0 + bq * 8;
            *(f16x8*)&BsH[bnr * GBK + cs * 8] = *(const f16x8*)&BtH[gb];
            *(f16x8*)&BsL[bnr * GBK + cs * 8] = *(const f16x8*)&BtL[gb];
        }
        __syncthreads();
        // ---- compute: 3-term split product
        f16x8 aH[4], aL[4], bH[2], bL[2];
#pragma unroll
        for (int i = 0; i < 4; ++i) {
            int r = wm * 64 + i * 16 + lr;
            int cs = lk ^ ((r >> 1) & 3);
            aH[i] = *(const f16x8*)&AsH[r * GBK + cs * 8];
            aL[i] = *(const f16x8*)&AsL[r * GBK + cs * 8];
        }
#pragma unroll
        for (int j = 0; j < 2; ++j) {
            int n = wn * 32 + j * 16 + lr;
            int cs = lk ^ ((n >> 1) & 3);
            bH[j] = *(const f16x8*)&BsH[n * GBK + cs * 8];
            bL[j] = *(const f16x8*)&BsL[n * GBK + cs * 8];
        }
#pragma unroll
        for (int i = 0; i < 4; ++i)
#pragma unroll
            for (int j = 0; j < 2; ++j) {
                acc[i][j] = __builtin_amdgcn_mfma_f32_16x16x32_f16(aH[i], bH[j], acc[i][j], 0, 0, 0);
                acc[i][j] = __builtin_amdgcn_mfma_f32_16x16x32_f16(aH[i], bL[j], acc[i][j], 0, 0, 0);
                acc[i][j] = __builtin_amdgcn_mfma_f32_16x16x32_f16(aL[i], bH[j], acc[i][j], 0, 0, 0);
            }
        __syncthreads();
    }
    // ---- epilogue: unscale, bias, act
    float inv_s = scv[1];
    float slope = (act == 2 && prelu) ? prelu[0] : 0.f;
#pragma unroll
    for (int i = 0; i < 4; ++i) {
        int rbase = bm + wm * 64 + i * 16 + lk * 4;
#pragma unroll
        for (int j = 0; j < 2; ++j) {
            int n = bn + wn * 32 + j * 16 + lr;
            if (n >= N) continue;
            float bv = bias[n];
#pragma unroll
            for (int q = 0; q < 4; ++q) {
                int m = rbase + q;
                if (m >= M) continue;
                float v = acc[i][j][q] * inv_s + bv;
                if (act == 1) v = fmaxf(v, 0.f);
                else if (act == 2) v = (v >= 0.f) ? v : slope * v;
                C[(size_t)m * ldc + n] = v;
            }
        }
    }
}

// ---------------------------------------------------------------- pooling
__global__ void pool_kernel(const float* __restrict__ h, const int* __restrict__ batch,
                            float* __restrict__ pooled) {
    int idx = blockIdx.x * blockDim.x + threadIdx.x;
    if (idx >= N_NODES * HID) return;
    int node = idx / HID;
    int f = idx - node * HID;
    atomicAdd(&pooled[(size_t)batch[node] * HID + f], h[idx]);
}

// ---------------------------------------------------------------- launch
extern "C" void kernel_launch(void* const* d_in, const int* in_sizes, int n_in,
                              void* d_out, int out_size, void* d_ws, size_t ws_size,
                              hipStream_t stream) {
    const float* x      = (const float*)d_in[0];
    const int*   eidx   = (const int*)d_in[1];
    const int*   batch  = (const int*)d_in[2];
    const float* W_proj = (const float*)d_in[3];
    const float* b_proj = (const float*)d_in[4];
    const float* W1     = (const float*)d_in[5];
    const float* b1     = (const float*)d_in[6];
    const float* W2     = (const float*)d_in[7];
    const float* b2     = (const float*)d_in[8];
    const float* W_sp   = (const float*)d_in[9];
    const float* b_sp   = (const float*)d_in[10];
    const float* prelu  = (const float*)d_in[11];

    const int* src = eidx;
    const int* dst = eidx + N_EDGES;

    const int KP_H = 320;   // HID padded to mult of 32
    const int NP_H = 320;   // HID padded to mult of 64
    const int KP_P = 128;   // NODE_IN
    const int PROJ_SZ  = NP_H * KP_P;       // 40960
    const int LAYER_SZ = NP_H * KP_H;       // 102400
    const int SP_SZ    = READOUT * KP_H;    // 327680

    // ---- workspace layout ----
    float* hA     = (float*)d_ws;                            // 15,000,000
    float* hB     = hA + (size_t)N_NODES * HID;              // 15,000,000
    float* pooled = hB + (size_t)N_NODES * HID;              // 307,200
    float* scales = pooled + (size_t)N_GRAPHS * HID;         // 12 slots * 4
    int*   cnt    = (int*)(scales + 48);
    int*   offs   = cnt + N_NODES;
    int*   cursor = offs + N_NODES + 1;
    int*   csr    = cursor + N_NODES;
    uintptr_t fp  = (uintptr_t)(csr + N_EDGES);
    fp = (fp + 15) & ~(uintptr_t)15;
    f16* projH = (f16*)fp;
    f16* projL = projH + PROJ_SZ;
    f16* w1H   = projL + PROJ_SZ;            // 5 * LAYER_SZ
    f16* w1L   = w1H + 5 * (size_t)LAYER_SZ;
    f16* w2H   = w1L + 5 * (size_t)LAYER_SZ;
    f16* w2L   = w2H + 5 * (size_t)LAYER_SZ;
    f16* spH   = w2L + 5 * (size_t)LAYER_SZ;
    f16* spL   = spH + SP_SZ;
    size_t needed = (size_t)((uintptr_t)(spL + SP_SZ) - (uintptr_t)d_ws);
    if (ws_size < needed) return;

    // ---- weight pre-split (once per call) ----
    split_weight<<<NP_H, 256, 0, stream>>>(W_proj, NODE_IN, HID, KP_P, projH, projL);
    for (int i = 0; i < DEPTH; ++i) {
        split_weight<<<NP_H, 256, 0, stream>>>(W1 + (size_t)i * HID * HID, HID, HID, KP_H,
                                               w1H + (size_t)i * LAYER_SZ, w1L + (size_t)i * LAYER_SZ);
        split_weight<<<NP_H, 256, 0, stream>>>(W2 + (size_t)i * HID * HID, HID, HID, KP_H,
                                               w2H + (size_t)i * LAYER_SZ, w2L + (size_t)i * LAYER_SZ);
    }
    split_weight<<<READOUT, 256, 0, stream>>>(W_sp, HID, READOUT, KP_H, spH, spL);

    // ---- CSR build ----
    hipMemsetAsync(cnt, 0, N_NODES * sizeof(int), stream);
    hipMemsetAsync(scales, 0, 48 * sizeof(float), stream);
    hist_kernel<<<(N_EDGES + 255) / 256, 256, 0, stream>>>(dst, cnt, N_EDGES);
    scan_kernel<<<1, 1024, 0, stream>>>(cnt, offs, cursor, N_NODES);
    scatter_kernel<<<(N_EDGES + 255) / 256, 256, 0, stream>>>(src, dst, cursor, csr, N_EDGES);

    auto run_amax = [&](const float* p, int n, int slot) {
        unsigned* u = (unsigned*)(scales + slot * 4);
        int blocks = (n + 255) / 256; if (blocks > 1024) blocks = 1024;
        amax_kernel<<<blocks, 256, 0, stream>>>(p, n, u);
        scale_from_amax<<<1, 1, 0, stream>>>(u, scales + slot * 4 + 1);
    };

    // ---- projection ----
    run_amax(x, N_NODES * NODE_IN, 0);
    {
        dim3 grid((NP_H + GBN - 1) / GBN, (N_NODES + GBM - 1) / GBM);
        gemm_split_f16<<<grid, 256, 0, stream>>>(x, NODE_IN, N_NODES, NODE_IN,
                                                 projH, projL, KP_P, b_proj, hA, HID, HID,
                                                 scales + 0 * 4 + 1, 1, nullptr);
    }

    float* cur = hA;
    float* alt = hB;
    dim3 ggrid((NP_H + GBN - 1) / GBN, (N_NODES + GBM - 1) / GBM);
    const int NH = N_NODES * HID;
    for (int i = 0; i < DEPTH; ++i) {
        aggregate_kernel<<<(N_NODES * 64 + 255) / 256, 256, 0, stream>>>(cur, offs, csr, alt);
        int s1 = 1 + 2 * i, s2 = 2 + 2 * i;
        run_amax(alt, NH, s1);
        gemm_split_f16<<<ggrid, 256, 0, stream>>>(alt, HID, N_NODES, HID,
                                                  w1H + (size_t)i * LAYER_SZ, w1L + (size_t)i * LAYER_SZ,
                                                  KP_H, b1 + (size_t)i * HID, cur, HID, HID,
                                                  scales + s1 * 4 + 1, 1, nullptr);
        run_amax(cur, NH, s2);
        gemm_split_f16<<<ggrid, 256, 0, stream>>>(cur, HID, N_NODES, HID,
                                                  w2H + (size_t)i * LAYER_SZ, w2L + (size_t)i * LAYER_SZ,
                                                  KP_H, b2 + (size_t)i * HID, alt, HID, HID,
                                                  scales + s2 * 4 + 1, (i < DEPTH - 1) ? 1 : 0, nullptr);
        float* tmp = cur; cur = alt; alt = tmp;
    }

    // ---- pooling ----
    hipMemsetAsync(pooled, 0, (size_t)N_GRAPHS * HID * sizeof(float), stream);
    pool_kernel<<<(N_NODES * HID + 255) / 256, 256, 0, stream>>>(cur, batch, pooled);

    // ---- readout ----
    run_amax(pooled, N_GRAPHS * HID, 11);
    {
        dim3 grid((READOUT + GBN - 1) / GBN, (N_GRAPHS + GBM - 1) / GBM);
        gemm_split_f16<<<grid, 256, 0, stream>>>(pooled, HID, N_GRAPHS, HID,
                                                 spH, spL, KP_H, b_sp, (float*)d_out, READOUT, READOUT,
                                                 scales + 11 * 4 + 1, 2, prelu);
    }
}

// Round 3
// 2095.943 us; speedup vs baseline: 1.6967x; 1.3837x over previous
//
#include <hip/hip_runtime.h>
#include <cstdint>

#define N_NODES 50000
#define N_EDGES 800000
#define N_GRAPHS 1024
#define NODE_IN 128
#define HID 300
#define DEPTH 5
#define READOUT 1024

typedef float f32x4 __attribute__((ext_vector_type(4)));
typedef short bf16x8 __attribute__((ext_vector_type(8)));
typedef unsigned short us8 __attribute__((ext_vector_type(8)));

__device__ inline unsigned short f2bf(float v) {
    unsigned u = __float_as_uint(v);
    unsigned r = u + 0x7FFFu + ((u >> 16) & 1u);
    return (unsigned short)(r >> 16);
}
__device__ inline float bf2f(unsigned short h) {
    return __uint_as_float((unsigned)h << 16);
}

// ---------------------------------------------------------------- CSR build
__global__ void hist_kernel(const int* __restrict__ dst, int* __restrict__ cnt, int n) {
    int i = blockIdx.x * blockDim.x + threadIdx.x;
    if (i < n) atomicAdd(&cnt[dst[i]], 1);
}

__global__ __launch_bounds__(256)
void scan_block(const int* __restrict__ in, int* __restrict__ out_excl,
                int* __restrict__ bsum, int n) {
    __shared__ int buf[256];
    int i = blockIdx.x * 256 + (int)threadIdx.x;
    int v = (i < n) ? in[i] : 0;
    buf[threadIdx.x] = v;
    __syncthreads();
    for (int off = 1; off < 256; off <<= 1) {
        int t = ((int)threadIdx.x >= off) ? buf[threadIdx.x - off] : 0;
        __syncthreads();
        buf[threadIdx.x] += t;
        __syncthreads();
    }
    if (i < n) out_excl[i] = buf[threadIdx.x] - v;
    if (threadIdx.x == 255) bsum[blockIdx.x] = buf[255];
}

__global__ __launch_bounds__(256)
void scan_base(const int* __restrict__ bsum, int* __restrict__ bbase, int nb,
               int* __restrict__ total) {
    __shared__ int buf[256];
    int v = ((int)threadIdx.x < nb) ? bsum[threadIdx.x] : 0;
    buf[threadIdx.x] = v;
    __syncthreads();
    for (int off = 1; off < 256; off <<= 1) {
        int t = ((int)threadIdx.x >= off) ? buf[threadIdx.x - off] : 0;
        __syncthreads();
        buf[threadIdx.x] += t;
        __syncthreads();
    }
    if ((int)threadIdx.x < nb) bbase[threadIdx.x] = buf[threadIdx.x] - v;
    if (threadIdx.x == 255) *total = buf[255];
}

__global__ void scan_add(int* __restrict__ offs, const int* __restrict__ bbase,
                         int* __restrict__ cursor, int n) {
    int i = blockIdx.x * blockDim.x + threadIdx.x;
    if (i < n) {
        int o = offs[i] + bbase[blockIdx.x];
        offs[i] = o;
        cursor[i] = o;
    }
}

__global__ void scatter_kernel(const int* __restrict__ src, const int* __restrict__ dst,
                               int* __restrict__ cursor, int* __restrict__ csr, int n) {
    int i = blockIdx.x * blockDim.x + threadIdx.x;
    if (i < n) {
        int p = atomicAdd(&cursor[dst[i]], 1);
        csr[p] = src[i];
    }
}

// ---------------------------------------------------------------- aggregation
__global__ __launch_bounds__(256)
void aggregate_kernel(const float* __restrict__ h, const int* __restrict__ offs,
                      const int* __restrict__ csr, float* __restrict__ out) {
    int wave = (int)((blockIdx.x * blockDim.x + threadIdx.x) >> 6);
    int lane = threadIdx.x & 63;
    if (wave >= N_NODES) return;
    const float* self = h + (size_t)wave * HID;
    float acc[5];
#pragma unroll
    for (int j = 0; j < 5; ++j) {
        int f = lane + j * 64;
        acc[j] = (f < HID) ? self[f] : 0.f;
    }
    int s = offs[wave], e = offs[wave + 1];
    for (int k = s; k < e; ++k) {
        const float* row = h + (size_t)csr[k] * HID;
#pragma unroll
        for (int j = 0; j < 5; ++j) {
            int f = lane + j * 64;
            if (f < HID) acc[j] += row[f];
        }
    }
    float* o = out + (size_t)wave * HID;
#pragma unroll
    for (int j = 0; j < 5; ++j) {
        int f = lane + j * 64;
        if (f < HID) o[f] = acc[j];
    }
}

// ---------------------------------------------------------------- weight pre-split
// W [K][N] fp32 -> hi/lo bf16 [NP][KP] (transposed, zero-padded)
__global__ void split_weight(const float* __restrict__ W, int K, int N, int KP,
                             unsigned short* __restrict__ H, unsigned short* __restrict__ L) {
    int n = blockIdx.x;
    for (int k = threadIdx.x; k < KP; k += blockDim.x) {
        float v = (k < K && n < N) ? W[(size_t)k * N + n] : 0.f;
        unsigned short hb = f2bf(v);
        H[(size_t)n * KP + k] = hb;
        L[(size_t)n * KP + k] = f2bf(v - bf2f(hb));
    }
}

// ---------------------------------------------------------------- GEMM
// C[M,N] = act( A[M,K](fp32) @ (BH+BL)[KP,N] + bias )
// tile 64 x 320, BK=32, 256 thr = 4 waves, wave tile 64x80 (4x5 frags)
// LDS rows padded 32->40 bf16 (80B): ds_read/ds_write both <=2-way (free)
__global__ __launch_bounds__(256)
void gemm_bplanes(const float* __restrict__ A, int lda, int M, int K,
                  const unsigned short* __restrict__ BH,
                  const unsigned short* __restrict__ BL, int KP,
                  const float* __restrict__ bias, int N,
                  float* __restrict__ C, int ldc,
                  int act, const float* __restrict__ prelu) {
    __shared__ __align__(16) unsigned short AsH[64 * 40];
    __shared__ __align__(16) unsigned short AsL[64 * 40];
    __shared__ __align__(16) unsigned short BsH[320 * 40];
    __shared__ __align__(16) unsigned short BsL[320 * 40];

    const int tid = threadIdx.x;
    const int bm = blockIdx.y * 64;
    const int bn = blockIdx.x * 320;
    const int wid = tid >> 6;
    const int lane = tid & 63;
    const int lr = lane & 15, lk = lane >> 4;

    f32x4 acc[4][5];
#pragma unroll
    for (int m = 0; m < 4; ++m)
#pragma unroll
        for (int n = 0; n < 5; ++n) acc[m][n] = (f32x4)0.f;

    const int ar = tid >> 2, ac = tid & 3;

    for (int k0 = 0; k0 < KP; k0 += 32) {
        // ---- stage A: fp32 -> bf16 hi/lo (staged exactly once: BN spans all N)
        {
            int gm = bm + ar;
            int k = k0 + ac * 8;
            float v[8];
#pragma unroll
            for (int j = 0; j < 8; ++j) v[j] = 0.f;
            if (gm < M) {
                if (k + 7 < K) {
                    float4 p0 = *(const float4*)&A[(size_t)gm * lda + k];
                    float4 p1 = *(const float4*)&A[(size_t)gm * lda + k + 4];
                    v[0] = p0.x; v[1] = p0.y; v[2] = p0.z; v[3] = p0.w;
                    v[4] = p1.x; v[5] = p1.y; v[6] = p1.z; v[7] = p1.w;
                } else {
#pragma unroll
                    for (int j = 0; j < 8; ++j)
                        if (k + j < K) v[j] = A[(size_t)gm * lda + k + j];
                }
            }
            us8 h, l;
#pragma unroll
            for (int j = 0; j < 8; ++j) {
                unsigned short hb = f2bf(v[j]);
                h[j] = hb;
                l[j] = f2bf(v[j] - bf2f(hb));
            }
            *(us8*)&AsH[ar * 40 + ac * 8] = h;
            *(us8*)&AsL[ar * 40 + ac * 8] = l;
        }
        // ---- stage B: pure copy of pre-split planes (L2-resident)
#pragma unroll
        for (int p = 0; p < 5; ++p) {
            int r = (tid >> 2) + p * 64;
            size_t gb = (size_t)(bn + r) * KP + k0 + ac * 8;
            *(us8*)&BsH[r * 40 + ac * 8] = *(const us8*)&BH[gb];
            *(us8*)&BsL[r * 40 + ac * 8] = *(const us8*)&BL[gb];
        }
        __syncthreads();
        // ---- 3-term split MFMA
        bf16x8 aH[4], aL[4];
#pragma unroll
        for (int m = 0; m < 4; ++m) {
            int r = m * 16 + lr;
            aH[m] = *(const bf16x8*)&AsH[r * 40 + lk * 8];
            aL[m] = *(const bf16x8*)&AsL[r * 40 + lk * 8];
        }
#pragma unroll
        for (int n = 0; n < 5; ++n) {
            int r = wid * 80 + n * 16 + lr;
            bf16x8 bh = *(const bf16x8*)&BsH[r * 40 + lk * 8];
            bf16x8 bl = *(const bf16x8*)&BsL[r * 40 + lk * 8];
#pragma unroll
            for (int m = 0; m < 4; ++m) {
                acc[m][n] = __builtin_amdgcn_mfma_f32_16x16x32_bf16(aH[m], bh, acc[m][n], 0, 0, 0);
                acc[m][n] = __builtin_amdgcn_mfma_f32_16x16x32_bf16(aH[m], bl, acc[m][n], 0, 0, 0);
                acc[m][n] = __builtin_amdgcn_mfma_f32_16x16x32_bf16(aL[m], bh, acc[m][n], 0, 0, 0);
            }
        }
        __syncthreads();
    }
    // ---- epilogue
    float slope = (act == 2) ? prelu[0] : 0.f;
#pragma unroll
    for (int n = 0; n < 5; ++n) {
        int col = bn + wid * 80 + n * 16 + lr;
        if (col >= N) continue;
        float bv = bias[col];
#pragma unroll
        for (int m = 0; m < 4; ++m) {
            int rbase = bm + m * 16 + lk * 4;
#pragma unroll
            for (int q = 0; q < 4; ++q) {
                int row = rbase + q;
                if (row >= M) continue;
                float v = acc[m][n][q] + bv;
                if (act == 1) v = fmaxf(v, 0.f);
                else if (act == 2) v = (v >= 0.f) ? v : slope * v;
                C[(size_t)row * ldc + col] = v;
            }
        }
    }
}

// ---------------------------------------------------------------- pooling
__global__ void pool_kernel(const float* __restrict__ h, const int* __restrict__ batch,
                            float* __restrict__ pooled) {
    int idx = blockIdx.x * blockDim.x + threadIdx.x;
    if (idx >= N_NODES * HID) return;
    int node = idx / HID;
    int f = idx - node * HID;
    atomicAdd(&pooled[(size_t)batch[node] * HID + f], h[idx]);
}

// ---------------------------------------------------------------- launch
extern "C" void kernel_launch(void* const* d_in, const int* in_sizes, int n_in,
                              void* d_out, int out_size, void* d_ws, size_t ws_size,
                              hipStream_t stream) {
    const float* x      = (const float*)d_in[0];
    const int*   eidx   = (const int*)d_in[1];
    const int*   batch  = (const int*)d_in[2];
    const float* W_proj = (const float*)d_in[3];
    const float* b_proj = (const float*)d_in[4];
    const float* W1     = (const float*)d_in[5];
    const float* b1     = (const float*)d_in[6];
    const float* W2     = (const float*)d_in[7];
    const float* b2     = (const float*)d_in[8];
    const float* W_sp   = (const float*)d_in[9];
    const float* b_sp   = (const float*)d_in[10];
    const float* prelu  = (const float*)d_in[11];

    const int* src = eidx;
    const int* dst = eidx + N_EDGES;

    const int KP_H  = 320;                 // K pad (mult of 32)
    const int NP_H  = 320;                 // N pad (mult of 320)
    const int KP_P  = 128;
    const int NP_SP = 1280;                // readout N pad
    const int PROJ_SZ  = NP_H * KP_P;      // 40960
    const int LAYER_SZ = NP_H * KP_H;      // 102400
    const int SP_SZ    = NP_SP * KP_H;     // 409600
    const int NB = (N_NODES + 255) / 256;  // 196 scan blocks

    // ---- workspace layout ----
    float* hA     = (float*)d_ws;                            // 15,000,000
    float* hB     = hA + (size_t)N_NODES * HID;              // 15,000,000
    float* pooled = hB + (size_t)N_NODES * HID;              // 307,200
    int*   cnt    = (int*)(pooled + (size_t)N_GRAPHS * HID); // 50,000
    int*   bsum   = cnt + N_NODES;                           // 256
    int*   bbase  = bsum + 256;                              // 256
    int*   offs   = bbase + 256;                             // 50,001
    int*   cursor = offs + N_NODES + 1;                      // 50,000
    int*   csr    = cursor + N_NODES;                        // 800,000
    uintptr_t fp  = (uintptr_t)(csr + N_EDGES);
    fp = (fp + 15) & ~(uintptr_t)15;
    unsigned short* projH = (unsigned short*)fp;
    unsigned short* projL = projH + PROJ_SZ;
    unsigned short* w1H   = projL + PROJ_SZ;
    unsigned short* w1L   = w1H + 5 * (size_t)LAYER_SZ;
    unsigned short* w2H   = w1L + 5 * (size_t)LAYER_SZ;
    unsigned short* w2L   = w2H + 5 * (size_t)LAYER_SZ;
    unsigned short* spH   = w2L + 5 * (size_t)LAYER_SZ;
    unsigned short* spL   = spH + SP_SZ;
    size_t needed = (size_t)((uintptr_t)(spL + SP_SZ) - (uintptr_t)d_ws);
    if (ws_size < needed) return;

    // ---- weight pre-split ----
    split_weight<<<NP_H, 256, 0, stream>>>(W_proj, NODE_IN, HID, KP_P, projH, projL);
    for (int i = 0; i < DEPTH; ++i) {
        split_weight<<<NP_H, 256, 0, stream>>>(W1 + (size_t)i * HID * HID, HID, HID, KP_H,
                                               w1H + (size_t)i * LAYER_SZ, w1L + (size_t)i * LAYER_SZ);
        split_weight<<<NP_H, 256, 0, stream>>>(W2 + (size_t)i * HID * HID, HID, HID, KP_H,
                                               w2H + (size_t)i * LAYER_SZ, w2L + (size_t)i * LAYER_SZ);
    }
    split_weight<<<NP_SP, 256, 0, stream>>>(W_sp, HID, READOUT, KP_H, spH, spL);

    // ---- CSR build ----
    hipMemsetAsync(cnt, 0, N_NODES * sizeof(int), stream);
    hist_kernel<<<(N_EDGES + 255) / 256, 256, 0, stream>>>(dst, cnt, N_EDGES);
    scan_block<<<NB, 256, 0, stream>>>(cnt, offs, bsum, N_NODES);
    scan_base<<<1, 256, 0, stream>>>(bsum, bbase, NB, offs + N_NODES);
    scan_add<<<NB, 256, 0, stream>>>(offs, bbase, cursor, N_NODES);
    scatter_kernel<<<(N_EDGES + 255) / 256, 256, 0, stream>>>(src, dst, cursor, csr, N_EDGES);

    // ---- projection: h = relu(x @ W_proj + b) ----
    dim3 ggrid(1, (N_NODES + 63) / 64);
    gemm_bplanes<<<ggrid, 256, 0, stream>>>(x, NODE_IN, N_NODES, NODE_IN,
                                            projH, projL, KP_P, b_proj, HID,
                                            hA, HID, 1, nullptr);

    float* cur = hA;
    float* alt = hB;
    for (int i = 0; i < DEPTH; ++i) {
        aggregate_kernel<<<(N_NODES * 64 + 255) / 256, 256, 0, stream>>>(cur, offs, csr, alt);
        gemm_bplanes<<<ggrid, 256, 0, stream>>>(alt, HID, N_NODES, HID,
                                                w1H + (size_t)i * LAYER_SZ, w1L + (size_t)i * LAYER_SZ,
                                                KP_H, b1 + (size_t)i * HID, HID,
                                                cur, HID, 1, nullptr);
        gemm_bplanes<<<ggrid, 256, 0, stream>>>(cur, HID, N_NODES, HID,
                                                w2H + (size_t)i * LAYER_SZ, w2L + (size_t)i * LAYER_SZ,
                                                KP_H, b2 + (size_t)i * HID, HID,
                                                alt, HID, (i < DEPTH - 1) ? 1 : 0, nullptr);
        float* tmp = cur; cur = alt; alt = tmp;
    }

    // ---- pooling ----
    hipMemsetAsync(pooled, 0, (size_t)N_GRAPHS * HID * sizeof(float), stream);
    pool_kernel<<<(N_NODES * HID + 255) / 256, 256, 0, stream>>>(cur, batch, pooled);

    // ---- readout: prelu(pooled @ W_sp + b_sp) ----
    {
        dim3 grid(NP_SP / 320, (N_GRAPHS + 63) / 64);
        gemm_bplanes<<<grid, 256, 0, stream>>>(pooled, HID, N_GRAPHS, HID,
                                               spH, spL, KP_H, b_sp, READOUT,
                                               (float*)d_out, READOUT, 2, prelu);
    }
}

// Round 4
// 1402.628 us; speedup vs baseline: 2.5353x; 1.4943x over previous
//
#include <hip/hip_runtime.h>
#include <cstdint>

#define N_NODES 50000
#define N_EDGES 800000
#define N_GRAPHS 1024
#define NODE_IN 128
#define HID 300
#define DEPTH 5
#define READOUT 1024
#define PSTR 304   // plane row stride (elements), 608B, 16B-aligned

typedef float f32x4 __attribute__((ext_vector_type(4)));
typedef short bf16x8 __attribute__((ext_vector_type(8)));
typedef unsigned short us8 __attribute__((ext_vector_type(8)));

__device__ inline unsigned short f2bf(float v) {
    unsigned u = __float_as_uint(v);
    unsigned r = u + 0x7FFFu + ((u >> 16) & 1u);
    return (unsigned short)(r >> 16);
}
__device__ inline float bf2f(unsigned short h) {
    return __uint_as_float((unsigned)h << 16);
}
__device__ inline unsigned packbf(float a, float b) {
    return (unsigned)f2bf(a) | ((unsigned)f2bf(b) << 16);
}

// ---------------------------------------------------------------- CSR build
__global__ void hist_kernel(const int* __restrict__ dst, int* __restrict__ cnt, int n) {
    int i = blockIdx.x * blockDim.x + threadIdx.x;
    if (i < n) atomicAdd(&cnt[dst[i]], 1);
}

__global__ __launch_bounds__(256)
void scan_block(const int* __restrict__ in, int* __restrict__ out_excl,
                int* __restrict__ bsum, int n) {
    __shared__ int buf[256];
    int i = blockIdx.x * 256 + (int)threadIdx.x;
    int v = (i < n) ? in[i] : 0;
    buf[threadIdx.x] = v;
    __syncthreads();
    for (int off = 1; off < 256; off <<= 1) {
        int t = ((int)threadIdx.x >= off) ? buf[threadIdx.x - off] : 0;
        __syncthreads();
        buf[threadIdx.x] += t;
        __syncthreads();
    }
    if (i < n) out_excl[i] = buf[threadIdx.x] - v;
    if (threadIdx.x == 255) bsum[blockIdx.x] = buf[255];
}

__global__ __launch_bounds__(256)
void scan_base(const int* __restrict__ bsum, int* __restrict__ bbase, int nb,
               int* __restrict__ total) {
    __shared__ int buf[256];
    int v = ((int)threadIdx.x < nb) ? bsum[threadIdx.x] : 0;
    buf[threadIdx.x] = v;
    __syncthreads();
    for (int off = 1; off < 256; off <<= 1) {
        int t = ((int)threadIdx.x >= off) ? buf[threadIdx.x - off] : 0;
        __syncthreads();
        buf[threadIdx.x] += t;
        __syncthreads();
    }
    if ((int)threadIdx.x < nb) bbase[threadIdx.x] = buf[threadIdx.x] - v;
    if (threadIdx.x == 255) *total = buf[255];
}

__global__ void scan_add(int* __restrict__ offs, const int* __restrict__ bbase,
                         int* __restrict__ cursor, int n) {
    int i = blockIdx.x * blockDim.x + threadIdx.x;
    if (i < n) {
        int o = offs[i] + bbase[blockIdx.x];
        offs[i] = o;
        cursor[i] = o;
    }
}

__global__ void scatter_kernel(const int* __restrict__ src, const int* __restrict__ dst,
                               int* __restrict__ cursor, int* __restrict__ csr, int n) {
    int i = blockIdx.x * blockDim.x + threadIdx.x;
    if (i < n) {
        int p = atomicAdd(&cursor[dst[i]], 1);
        csr[p] = src[i];
    }
}

// ---------------------------------------------------------------- aggregation (bf16 planes)
// out[node] = h[node] + sum_{e: dst==node} h[src[e]]; rows are PSTR bf16, read as dwords
__global__ __launch_bounds__(256)
void aggregate_bf16(const unsigned short* __restrict__ h, const int* __restrict__ offs,
                    const int* __restrict__ csr, unsigned short* __restrict__ out) {
    int wave = (int)((blockIdx.x * blockDim.x + threadIdx.x) >> 6);
    int lane = threadIdx.x & 63;
    if (wave >= N_NODES) return;
    float a0, a1, a2, a3, a4 = 0.f, a5 = 0.f;
    {
        const unsigned* r = (const unsigned*)(h + (size_t)wave * PSTR);
        unsigned u0 = r[lane], u1 = r[64 + lane];
        a0 = bf2f((unsigned short)u0); a1 = bf2f((unsigned short)(u0 >> 16));
        a2 = bf2f((unsigned short)u1); a3 = bf2f((unsigned short)(u1 >> 16));
        if (lane < 22) {
            unsigned u2 = r[128 + lane];
            a4 = bf2f((unsigned short)u2); a5 = bf2f((unsigned short)(u2 >> 16));
        }
    }
    int s = offs[wave], e = offs[wave + 1];
    for (int k = s; k < e; ++k) {
        const unsigned* r = (const unsigned*)(h + (size_t)csr[k] * PSTR);
        unsigned u0 = r[lane], u1 = r[64 + lane];
        a0 += bf2f((unsigned short)u0); a1 += bf2f((unsigned short)(u0 >> 16));
        a2 += bf2f((unsigned short)u1); a3 += bf2f((unsigned short)(u1 >> 16));
        if (lane < 22) {
            unsigned u2 = r[128 + lane];
            a4 += bf2f((unsigned short)u2); a5 += bf2f((unsigned short)(u2 >> 16));
        }
    }
    unsigned* o = (unsigned*)(out + (size_t)wave * PSTR);
    o[lane] = packbf(a0, a1);
    o[64 + lane] = packbf(a2, a3);
    if (lane < 24) o[128 + lane] = (lane < 22) ? packbf(a4, a5) : 0u;  // pad cols 300..303 = 0
}

// ---------------------------------------------------------------- weight pre-split (coalesced transpose)
// W [K][N] fp32 -> H/L bf16 [NP][KP]
__global__ __launch_bounds__(256)
void split_weight_t(const float* __restrict__ W, int K, int N, int KP,
                    unsigned short* __restrict__ H, unsigned short* __restrict__ L) {
    __shared__ float tile[32][33];
    int n0 = blockIdx.x * 32, k0 = blockIdx.y * 32;
    int tx = threadIdx.x & 31, ty = threadIdx.x >> 5;  // ty 0..7
#pragma unroll
    for (int r = 0; r < 4; ++r) {
        int k = k0 + ty + r * 8, n = n0 + tx;
        tile[ty + r * 8][tx] = (k < K && n < N) ? W[(size_t)k * N + n] : 0.f;
    }
    __syncthreads();
#pragma unroll
    for (int r = 0; r < 4; ++r) {
        int n = n0 + ty + r * 8, k = k0 + tx;
        float v = tile[tx][ty + r * 8];
        unsigned short hb = f2bf(v);
        H[(size_t)n * KP + k] = hb;
        L[(size_t)n * KP + k] = f2bf(v - bf2f(hb));
    }
}

// ---------------------------------------------------------------- GEMM: bf16-plane A
// Out[M,300] = act( A(bf16 plane) @ (BH+BL) + bias ) -> bf16 plane. tile 64x320, KP=320
__global__ __launch_bounds__(256)
void gemm_planeA(const unsigned short* __restrict__ Ap, int M,
                 const unsigned short* __restrict__ BH, const unsigned short* __restrict__ BL,
                 const float* __restrict__ bias, int N,
                 unsigned short* __restrict__ Op, int act) {
    __shared__ __align__(16) unsigned short As[64 * 40];
    __shared__ __align__(16) unsigned short BsH[320 * 40];
    __shared__ __align__(16) unsigned short BsL[320 * 40];

    const int tid = threadIdx.x;
    const int bm = blockIdx.x * 64;
    const int wid = tid >> 6, lane = tid & 63;
    const int lr = lane & 15, lk = lane >> 4;
    const int ar = tid >> 2, ac = tid & 3;

    f32x4 acc[4][5];
#pragma unroll
    for (int m = 0; m < 4; ++m)
#pragma unroll
        for (int n = 0; n < 5; ++n) acc[m][n] = (f32x4)0.f;

    for (int k0 = 0; k0 < 320; k0 += 32) {
        {
            int gr = bm + ar; if (gr >= M) gr = M - 1;  // clamp (values discarded)
            *(us8*)&As[ar * 40 + ac * 8] = *(const us8*)&Ap[(size_t)gr * PSTR + k0 + ac * 8];
        }
#pragma unroll
        for (int p = 0; p < 5; ++p) {
            int r = ar + p * 64;
            size_t gb = (size_t)r * 320 + k0 + ac * 8;
            *(us8*)&BsH[r * 40 + ac * 8] = *(const us8*)&BH[gb];
            *(us8*)&BsL[r * 40 + ac * 8] = *(const us8*)&BL[gb];
        }
        __syncthreads();
        bf16x8 aS[4];
#pragma unroll
        for (int m = 0; m < 4; ++m)
            aS[m] = *(const bf16x8*)&As[(m * 16 + lr) * 40 + lk * 8];
#pragma unroll
        for (int n = 0; n < 5; ++n) {
            int r = wid * 80 + n * 16 + lr;
            bf16x8 bh = *(const bf16x8*)&BsH[r * 40 + lk * 8];
            bf16x8 bl = *(const bf16x8*)&BsL[r * 40 + lk * 8];
#pragma unroll
            for (int m = 0; m < 4; ++m) {
                acc[m][n] = __builtin_amdgcn_mfma_f32_16x16x32_bf16(aS[m], bh, acc[m][n], 0, 0, 0);
                acc[m][n] = __builtin_amdgcn_mfma_f32_16x16x32_bf16(aS[m], bl, acc[m][n], 0, 0, 0);
            }
        }
        __syncthreads();
    }
#pragma unroll
    for (int n = 0; n < 5; ++n) {
        int col = wid * 80 + n * 16 + lr;
        if (col >= PSTR) continue;
        bool vc = col < N;
        float bv = vc ? bias[col] : 0.f;
#pragma unroll
        for (int m = 0; m < 4; ++m) {
            int rbase = bm + m * 16 + lk * 4;
#pragma unroll
            for (int q = 0; q < 4; ++q) {
                int row = rbase + q;
                if (row >= M) continue;
                float v = vc ? (acc[m][n][q] + bv) : 0.f;
                if (act == 1) v = fmaxf(v, 0.f);
                Op[(size_t)row * PSTR + col] = f2bf(v);
            }
        }
    }
}

// ---------------------------------------------------------------- GEMM: fp32 A (3-term split)
// used for projection (out->bf16 plane, relu) and readout (out->f32, prelu)
__global__ __launch_bounds__(256)
void gemm_f32A(const float* __restrict__ A, int lda, int M, int K, int KP,
               const unsigned short* __restrict__ BH, const unsigned short* __restrict__ BL, int KPB,
               const float* __restrict__ bias, int N,
               float* __restrict__ C, int ldc, unsigned short* __restrict__ Op, int outPlane,
               int act, const float* __restrict__ prelu) {
    __shared__ __align__(16) unsigned short AsH[64 * 40];
    __shared__ __align__(16) unsigned short AsL[64 * 40];
    __shared__ __align__(16) unsigned short BsH[320 * 40];
    __shared__ __align__(16) unsigned short BsL[320 * 40];

    const int tid = threadIdx.x;
    const int bm = blockIdx.y * 64;
    const int bn = blockIdx.x * 320;
    const int wid = tid >> 6, lane = tid & 63;
    const int lr = lane & 15, lk = lane >> 4;
    const int ar = tid >> 2, ac = tid & 3;

    f32x4 acc[4][5];
#pragma unroll
    for (int m = 0; m < 4; ++m)
#pragma unroll
        for (int n = 0; n < 5; ++n) acc[m][n] = (f32x4)0.f;

    for (int k0 = 0; k0 < KP; k0 += 32) {
        {
            int gm = bm + ar;
            int k = k0 + ac * 8;
            float v[8];
#pragma unroll
            for (int j = 0; j < 8; ++j) v[j] = 0.f;
            if (gm < M) {
                if (k + 7 < K) {
                    float4 p0 = *(const float4*)&A[(size_t)gm * lda + k];
                    float4 p1 = *(const float4*)&A[(size_t)gm * lda + k + 4];
                    v[0] = p0.x; v[1] = p0.y; v[2] = p0.z; v[3] = p0.w;
                    v[4] = p1.x; v[5] = p1.y; v[6] = p1.z; v[7] = p1.w;
                } else {
#pragma unroll
                    for (int j = 0; j < 8; ++j)
                        if (k + j < K) v[j] = A[(size_t)gm * lda + k + j];
                }
            }
            us8 h, l;
#pragma unroll
            for (int j = 0; j < 8; ++j) {
                unsigned short hb = f2bf(v[j]);
                h[j] = hb;
                l[j] = f2bf(v[j] - bf2f(hb));
            }
            *(us8*)&AsH[ar * 40 + ac * 8] = h;
            *(us8*)&AsL[ar * 40 + ac * 8] = l;
        }
#pragma unroll
        for (int p = 0; p < 5; ++p) {
            int r = ar + p * 64;
            size_t gb = (size_t)(bn + r) * KPB + k0 + ac * 8;
            *(us8*)&BsH[r * 40 + ac * 8] = *(const us8*)&BH[gb];
            *(us8*)&BsL[r * 40 + ac * 8] = *(const us8*)&BL[gb];
        }
        __syncthreads();
        bf16x8 aH[4], aL[4];
#pragma unroll
        for (int m = 0; m < 4; ++m) {
            aH[m] = *(const bf16x8*)&AsH[(m * 16 + lr) * 40 + lk * 8];
            aL[m] = *(const bf16x8*)&AsL[(m * 16 + lr) * 40 + lk * 8];
        }
#pragma unroll
        for (int n = 0; n < 5; ++n) {
            int r = wid * 80 + n * 16 + lr;
            bf16x8 bh = *(const bf16x8*)&BsH[r * 40 + lk * 8];
            bf16x8 bl = *(const bf16x8*)&BsL[r * 40 + lk * 8];
#pragma unroll
            for (int m = 0; m < 4; ++m) {
                acc[m][n] = __builtin_amdgcn_mfma_f32_16x16x32_bf16(aH[m], bh, acc[m][n], 0, 0, 0);
                acc[m][n] = __builtin_amdgcn_mfma_f32_16x16x32_bf16(aH[m], bl, acc[m][n], 0, 0, 0);
                acc[m][n] = __builtin_amdgcn_mfma_f32_16x16x32_bf16(aL[m], bh, acc[m][n], 0, 0, 0);
            }
        }
        __syncthreads();
    }
    float slope = (act == 2) ? prelu[0] : 0.f;
#pragma unroll
    for (int n = 0; n < 5; ++n) {
        int col = bn + wid * 80 + n * 16 + lr;
        bool vc = col < N;
        float bv = vc ? bias[col] : 0.f;
#pragma unroll
        for (int m = 0; m < 4; ++m) {
            int rbase = bm + m * 16 + lk * 4;
#pragma unroll
            for (int q = 0; q < 4; ++q) {
                int row = rbase + q;
                if (row >= M) continue;
                float v = vc ? (acc[m][n][q] + bv) : 0.f;
                if (act == 1) v = fmaxf(v, 0.f);
                else if (act == 2) v = (v >= 0.f) ? v : slope * v;
                if (outPlane) {
                    if (col < PSTR) Op[(size_t)row * PSTR + col] = f2bf(v);
                } else if (vc) {
                    C[(size_t)row * ldc + col] = v;
                }
            }
        }
    }
}

// ---------------------------------------------------------------- segmented pool
__global__ __launch_bounds__(64)
void pool_seg(const unsigned short* __restrict__ h, const int* __restrict__ goffs,
              float* __restrict__ pooled) {
    int g = blockIdx.x;
    int lane = threadIdx.x;
    int s = goffs[g], e = goffs[g + 1];
    float a0 = 0.f, a1 = 0.f, a2 = 0.f, a3 = 0.f, a4 = 0.f, a5 = 0.f;
    for (int node = s; node < e; ++node) {
        const unsigned* r = (const unsigned*)(h + (size_t)node * PSTR);
        unsigned u0 = r[lane], u1 = r[64 + lane];
        a0 += bf2f((unsigned short)u0); a1 += bf2f((unsigned short)(u0 >> 16));
        a2 += bf2f((unsigned short)u1); a3 += bf2f((unsigned short)(u1 >> 16));
        if (lane < 22) {
            unsigned u2 = r[128 + lane];
            a4 += bf2f((unsigned short)u2); a5 += bf2f((unsigned short)(u2 >> 16));
        }
    }
    float* pr = pooled + (size_t)g * PSTR;
    *(float2*)&pr[2 * lane] = make_float2(a0, a1);
    *(float2*)&pr[128 + 2 * lane] = make_float2(a2, a3);
    if (lane < 24) {
        float2 t = (lane < 22) ? make_float2(a4, a5) : make_float2(0.f, 0.f);
        *(float2*)&pr[256 + 2 * lane] = t;
    }
}

// ---------------------------------------------------------------- launch
extern "C" void kernel_launch(void* const* d_in, const int* in_sizes, int n_in,
                              void* d_out, int out_size, void* d_ws, size_t ws_size,
                              hipStream_t stream) {
    const float* x      = (const float*)d_in[0];
    const int*   eidx   = (const int*)d_in[1];
    const int*   batch  = (const int*)d_in[2];
    const float* W_proj = (const float*)d_in[3];
    const float* b_proj = (const float*)d_in[4];
    const float* W1     = (const float*)d_in[5];
    const float* b1     = (const float*)d_in[6];
    const float* W2     = (const float*)d_in[7];
    const float* b2     = (const float*)d_in[8];
    const float* W_sp   = (const float*)d_in[9];
    const float* b_sp   = (const float*)d_in[10];
    const float* prelu  = (const float*)d_in[11];

    const int* src = eidx;
    const int* dst = eidx + N_EDGES;

    const size_t PLANE = (size_t)N_NODES * PSTR + 64;   // +slack for tail over-read
    const int LAYER_SZ = 320 * 320;
    const int PROJ_SZ  = 320 * 128;
    const int SP_SZ    = 1280 * 320;
    const int NB  = (N_NODES + 255) / 256;   // 196
    const int NBG = (N_GRAPHS + 255) / 256;  // 4

    // ---- workspace layout ----
    unsigned short* hplane = (unsigned short*)d_ws;
    unsigned short* aggp   = hplane + PLANE;
    unsigned short* tp     = aggp + PLANE;
    float* pooled = (float*)(tp + PLANE);                      // 1024*304+16 floats
    unsigned short* projH = (unsigned short*)(pooled + (size_t)N_GRAPHS * PSTR + 16);
    unsigned short* projL = projH + PROJ_SZ;
    unsigned short* w1H   = projL + PROJ_SZ;
    unsigned short* w1L   = w1H + 5 * (size_t)LAYER_SZ;
    unsigned short* w2H   = w1L + 5 * (size_t)LAYER_SZ;
    unsigned short* w2L   = w2H + 5 * (size_t)LAYER_SZ;
    unsigned short* spH   = w2L + 5 * (size_t)LAYER_SZ;
    unsigned short* spL   = spH + SP_SZ;
    int* cnt    = (int*)(((uintptr_t)(spL + SP_SZ) + 15) & ~(uintptr_t)15);
    int* bsum   = cnt + N_NODES;
    int* bbase  = bsum + 256;
    int* offs   = bbase + 256;
    int* cursor = offs + N_NODES + 1;
    int* csr    = cursor + N_NODES;
    int* gcnt   = csr + N_EDGES;
    int* gsum   = gcnt + N_GRAPHS;
    int* gbase  = gsum + 256;
    int* goffs  = gbase + 256;
    int* gcur   = goffs + N_GRAPHS + 1;
    size_t needed = (size_t)((uintptr_t)(gcur + N_GRAPHS) - (uintptr_t)d_ws);
    if (ws_size < needed) return;

    // ---- weight pre-split (coalesced transpose) ----
    split_weight_t<<<dim3(10, 4), 256, 0, stream>>>(W_proj, NODE_IN, HID, 128, projH, projL);
    for (int i = 0; i < DEPTH; ++i) {
        split_weight_t<<<dim3(10, 10), 256, 0, stream>>>(W1 + (size_t)i * HID * HID, HID, HID, 320,
                                                         w1H + (size_t)i * LAYER_SZ, w1L + (size_t)i * LAYER_SZ);
        split_weight_t<<<dim3(10, 10), 256, 0, stream>>>(W2 + (size_t)i * HID * HID, HID, HID, 320,
                                                         w2H + (size_t)i * LAYER_SZ, w2L + (size_t)i * LAYER_SZ);
    }
    split_weight_t<<<dim3(40, 10), 256, 0, stream>>>(W_sp, HID, READOUT, 320, spH, spL);

    // ---- CSR build (by dst) ----
    hipMemsetAsync(cnt, 0, N_NODES * sizeof(int), stream);
    hipMemsetAsync(gcnt, 0, N_GRAPHS * sizeof(int), stream);
    hist_kernel<<<(N_EDGES + 255) / 256, 256, 0, stream>>>(dst, cnt, N_EDGES);
    scan_block<<<NB, 256, 0, stream>>>(cnt, offs, bsum, N_NODES);
    scan_base<<<1, 256, 0, stream>>>(bsum, bbase, NB, offs + N_NODES);
    scan_add<<<NB, 256, 0, stream>>>(offs, bbase, cursor, N_NODES);
    scatter_kernel<<<(N_EDGES + 255) / 256, 256, 0, stream>>>(src, dst, cursor, csr, N_EDGES);

    // ---- graph offsets for pooling (batch is sorted) ----
    hist_kernel<<<(N_NODES + 255) / 256, 256, 0, stream>>>(batch, gcnt, N_NODES);
    scan_block<<<NBG, 256, 0, stream>>>(gcnt, goffs, gsum, N_GRAPHS);
    scan_base<<<1, 256, 0, stream>>>(gsum, gbase, NBG, goffs + N_GRAPHS);
    scan_add<<<NBG, 256, 0, stream>>>(goffs, gbase, gcur, N_GRAPHS);

    // ---- projection: h0 = relu(x @ W_proj + b) -> bf16 plane ----
    gemm_f32A<<<dim3(1, (N_NODES + 63) / 64), 256, 0, stream>>>(
        x, NODE_IN, N_NODES, NODE_IN, 128, projH, projL, 128,
        b_proj, HID, nullptr, 0, hplane, 1, 1, nullptr);

    // ---- GIN layers ----
    for (int i = 0; i < DEPTH; ++i) {
        aggregate_bf16<<<(N_NODES * 64 + 255) / 256, 256, 0, stream>>>(hplane, offs, csr, aggp);
        gemm_planeA<<<(N_NODES + 63) / 64, 256, 0, stream>>>(
            aggp, N_NODES, w1H + (size_t)i * LAYER_SZ, w1L + (size_t)i * LAYER_SZ,
            b1 + (size_t)i * HID, HID, tp, 1);
        gemm_planeA<<<(N_NODES + 63) / 64, 256, 0, stream>>>(
            tp, N_NODES, w2H + (size_t)i * LAYER_SZ, w2L + (size_t)i * LAYER_SZ,
            b2 + (size_t)i * HID, HID, hplane, (i < DEPTH - 1) ? 1 : 0);
    }

    // ---- segmented pool over sorted batch ----
    pool_seg<<<N_GRAPHS, 64, 0, stream>>>(hplane, goffs, pooled);

    // ---- readout: prelu(pooled @ W_sp + b_sp) -> d_out (fp32) ----
    gemm_f32A<<<dim3(4, (N_GRAPHS + 63) / 64), 256, 0, stream>>>(
        pooled, PSTR, N_GRAPHS, HID, 320, spH, spL, 320,
        b_sp, READOUT, (float*)d_out, READOUT, nullptr, 0, 2, prelu);
}

// Round 5
// 1354.918 us; speedup vs baseline: 2.6246x; 1.0352x over previous
//
#include <hip/hip_runtime.h>
#include <cstdint>

#define N_NODES 50000
#define N_EDGES 800000
#define N_GRAPHS 1024
#define NODE_IN 128
#define HID 300
#define DEPTH 5
#define READOUT 1024
#define PSTR 304   // plane row stride (elements), 608B, 16B-aligned

typedef float f32x4 __attribute__((ext_vector_type(4)));
typedef short bf16x8 __attribute__((ext_vector_type(8)));
typedef unsigned short us8 __attribute__((ext_vector_type(8)));

__device__ inline unsigned short f2bf(float v) {
    unsigned u = __float_as_uint(v);
    unsigned r = u + 0x7FFFu + ((u >> 16) & 1u);
    return (unsigned short)(r >> 16);
}
__device__ inline float bf2f(unsigned short h) {
    return __uint_as_float((unsigned)h << 16);
}
__device__ inline unsigned packbf(float a, float b) {
    return (unsigned)f2bf(a) | ((unsigned)f2bf(b) << 16);
}

// ---------------------------------------------------------------- CSR build
__global__ void hist_kernel(const int* __restrict__ dst, int* __restrict__ cnt, int n) {
    int i = blockIdx.x * blockDim.x + threadIdx.x;
    if (i < n) atomicAdd(&cnt[dst[i]], 1);
}

__global__ __launch_bounds__(256)
void scan_block(const int* __restrict__ in, int* __restrict__ out_excl,
                int* __restrict__ bsum, int n) {
    __shared__ int buf[256];
    int i = blockIdx.x * 256 + (int)threadIdx.x;
    int v = (i < n) ? in[i] : 0;
    buf[threadIdx.x] = v;
    __syncthreads();
    for (int off = 1; off < 256; off <<= 1) {
        int t = ((int)threadIdx.x >= off) ? buf[threadIdx.x - off] : 0;
        __syncthreads();
        buf[threadIdx.x] += t;
        __syncthreads();
    }
    if (i < n) out_excl[i] = buf[threadIdx.x] - v;
    if (threadIdx.x == 255) bsum[blockIdx.x] = buf[255];
}

__global__ __launch_bounds__(256)
void scan_base(const int* __restrict__ bsum, int* __restrict__ bbase, int nb,
               int* __restrict__ total) {
    __shared__ int buf[256];
    int v = ((int)threadIdx.x < nb) ? bsum[threadIdx.x] : 0;
    buf[threadIdx.x] = v;
    __syncthreads();
    for (int off = 1; off < 256; off <<= 1) {
        int t = ((int)threadIdx.x >= off) ? buf[threadIdx.x - off] : 0;
        __syncthreads();
        buf[threadIdx.x] += t;
        __syncthreads();
    }
    if ((int)threadIdx.x < nb) bbase[threadIdx.x] = buf[threadIdx.x] - v;
    if (threadIdx.x == 255) *total = buf[255];
}

__global__ void scan_add(int* __restrict__ offs, const int* __restrict__ bbase,
                         int* __restrict__ cursor, int n) {
    int i = blockIdx.x * blockDim.x + threadIdx.x;
    if (i < n) {
        int o = offs[i] + bbase[blockIdx.x];
        offs[i] = o;
        cursor[i] = o;
    }
}

__global__ void scatter_kernel(const int* __restrict__ src, const int* __restrict__ dst,
                               int* __restrict__ cursor, int* __restrict__ csr, int n) {
    int i = blockIdx.x * blockDim.x + threadIdx.x;
    if (i < n) {
        int p = atomicAdd(&cursor[dst[i]], 1);
        csr[p] = src[i];
    }
}

// ---------------------------------------------------------------- aggregation (bf16 planes)
__global__ __launch_bounds__(256)
void aggregate_bf16(const unsigned short* __restrict__ h, const int* __restrict__ offs,
                    const int* __restrict__ csr, unsigned short* __restrict__ out) {
    int wave = (int)((blockIdx.x * blockDim.x + threadIdx.x) >> 6);
    int lane = threadIdx.x & 63;
    if (wave >= N_NODES) return;
    float a0, a1, a2, a3, a4 = 0.f, a5 = 0.f;
    {
        const unsigned* r = (const unsigned*)(h + (size_t)wave * PSTR);
        unsigned u0 = r[lane], u1 = r[64 + lane];
        a0 = bf2f((unsigned short)u0); a1 = bf2f((unsigned short)(u0 >> 16));
        a2 = bf2f((unsigned short)u1); a3 = bf2f((unsigned short)(u1 >> 16));
        if (lane < 22) {
            unsigned u2 = r[128 + lane];
            a4 = bf2f((unsigned short)u2); a5 = bf2f((unsigned short)(u2 >> 16));
        }
    }
    int s = offs[wave], e = offs[wave + 1];
    for (int k = s; k < e; ++k) {
        const unsigned* r = (const unsigned*)(h + (size_t)csr[k] * PSTR);
        unsigned u0 = r[lane], u1 = r[64 + lane];
        a0 += bf2f((unsigned short)u0); a1 += bf2f((unsigned short)(u0 >> 16));
        a2 += bf2f((unsigned short)u1); a3 += bf2f((unsigned short)(u1 >> 16));
        if (lane < 22) {
            unsigned u2 = r[128 + lane];
            a4 += bf2f((unsigned short)u2); a5 += bf2f((unsigned short)(u2 >> 16));
        }
    }
    unsigned* o = (unsigned*)(out + (size_t)wave * PSTR);
    o[lane] = packbf(a0, a1);
    o[64 + lane] = packbf(a2, a3);
    if (lane < 24) o[128 + lane] = (lane < 22) ? packbf(a4, a5) : 0u;
}

// ---------------------------------------------------------------- weight pre-split (coalesced transpose)
__global__ __launch_bounds__(256)
void split_weight_t(const float* __restrict__ W, int K, int N, int KP,
                    unsigned short* __restrict__ H, unsigned short* __restrict__ L) {
    __shared__ float tile[32][33];
    int n0 = blockIdx.x * 32, k0 = blockIdx.y * 32;
    int tx = threadIdx.x & 31, ty = threadIdx.x >> 5;
#pragma unroll
    for (int r = 0; r < 4; ++r) {
        int k = k0 + ty + r * 8, n = n0 + tx;
        tile[ty + r * 8][tx] = (k < K && n < N) ? W[(size_t)k * N + n] : 0.f;
    }
    __syncthreads();
#pragma unroll
    for (int r = 0; r < 4; ++r) {
        int n = n0 + ty + r * 8, k = k0 + tx;
        float v = tile[tx][ty + r * 8];
        unsigned short hb = f2bf(v);
        H[(size_t)n * KP + k] = hb;
        L[(size_t)n * KP + k] = f2bf(v - bf2f(hb));
    }
}

// ---------------------------------------------------------------- hidden GEMM (pipelined)
// Out[M,300] = act( A(bf16 plane, K=320) @ (BH+BL)[320x320] + bias ) -> bf16 plane
// tile 64x320, BK=32, 4 waves (wave tile 64x80), reg-prefetch software pipeline.
// B LDS: 32-wide rows + XOR chunk swizzle (2-way max = free). A LDS: pad-40 rows.
#define BSWZ(r, c) ((c) ^ (((r) >> 1) & 3))
__global__ __launch_bounds__(256)
void gemm_plane2(const unsigned short* __restrict__ Ap, int M,
                 const unsigned short* __restrict__ BH, const unsigned short* __restrict__ BL,
                 const float* __restrict__ bias, unsigned short* __restrict__ Op, int act) {
    __shared__ __align__(16) unsigned short As[64 * 40];
    __shared__ __align__(16) unsigned short BsH[320 * 32];
    __shared__ __align__(16) unsigned short BsL[320 * 32];

    const int tid = threadIdx.x;
    const int bm = blockIdx.x * 64;
    const int wid = tid >> 6, lane = tid & 63;
    const int lr = lane & 15, lk = lane >> 4;
    const int arow = tid >> 2, ac = tid & 3;

    int agr = bm + arow; if (agr >= M) agr = M - 1;       // clamp; discarded later
    const unsigned short* aSrc = Ap + (size_t)agr * PSTR + ac * 8;

    f32x4 acc[4][5];
#pragma unroll
    for (int m = 0; m < 4; ++m)
#pragma unroll
        for (int n = 0; n < 5; ++n) acc[m][n] = (f32x4)0.f;

    // prefetch K-tile 0
    us8 aPre, bPreH[5], bPreL[5];
    aPre = *(const us8*)&aSrc[0];
#pragma unroll
    for (int i = 0; i < 5; ++i) {
        int f = tid + i * 256;
        int r = f >> 2, c = f & 3;
        bPreH[i] = *(const us8*)&BH[(size_t)r * 320 + c * 8];
        bPreL[i] = *(const us8*)&BL[(size_t)r * 320 + c * 8];
    }

    for (int t = 0; t < 10; ++t) {
        if (t) __syncthreads();                 // compute(t-1) done reading LDS
        // write staged regs -> LDS
        *(us8*)&As[arow * 40 + ac * 8] = aPre;
#pragma unroll
        for (int i = 0; i < 5; ++i) {
            int f = tid + i * 256;
            int r = f >> 2, c = f & 3;
            int idx = r * 32 + BSWZ(r, c) * 8;
            *(us8*)&BsH[idx] = bPreH[i];
            *(us8*)&BsL[idx] = bPreL[i];
        }
        __syncthreads();
        // issue next-tile global loads (overlap with MFMA below)
        if (t < 9) {
            int k = (t + 1) * 32;
            aPre = *(const us8*)&aSrc[k];
#pragma unroll
            for (int i = 0; i < 5; ++i) {
                int f = tid + i * 256;
                int r = f >> 2, c = f & 3;
                bPreH[i] = *(const us8*)&BH[(size_t)r * 320 + k + c * 8];
                bPreL[i] = *(const us8*)&BL[(size_t)r * 320 + k + c * 8];
            }
        }
        // compute: 40 MFMA
        bf16x8 aS[4];
#pragma unroll
        for (int m = 0; m < 4; ++m)
            aS[m] = *(const bf16x8*)&As[(m * 16 + lr) * 40 + lk * 8];
#pragma unroll
        for (int n = 0; n < 5; ++n) {
            int r = wid * 80 + n * 16 + lr;
            int sc = r * 32 + BSWZ(r, lk) * 8;
            bf16x8 bh = *(const bf16x8*)&BsH[sc];
            bf16x8 bl = *(const bf16x8*)&BsL[sc];
#pragma unroll
            for (int m = 0; m < 4; ++m) {
                acc[m][n] = __builtin_amdgcn_mfma_f32_16x16x32_bf16(aS[m], bh, acc[m][n], 0, 0, 0);
                acc[m][n] = __builtin_amdgcn_mfma_f32_16x16x32_bf16(aS[m], bl, acc[m][n], 0, 0, 0);
            }
        }
    }
    // epilogue
#pragma unroll
    for (int n = 0; n < 5; ++n) {
        int col = wid * 80 + n * 16 + lr;
        bool vc = col < HID;
        float bv = vc ? bias[col] : 0.f;
#pragma unroll
        for (int m = 0; m < 4; ++m) {
            int rbase = bm + m * 16 + lk * 4;
#pragma unroll
            for (int q = 0; q < 4; ++q) {
                int row = rbase + q;
                if (row >= M) continue;
                float v = vc ? (acc[m][n][q] + bv) : 0.f;
                if (act == 1) v = fmaxf(v, 0.f);
                if (col < PSTR) Op[(size_t)row * PSTR + col] = f2bf(v);
            }
        }
    }
}

// ---------------------------------------------------------------- GEMM: fp32 A (3-term split)
__global__ __launch_bounds__(256)
void gemm_f32A(const float* __restrict__ A, int lda, int M, int K, int KP,
               const unsigned short* __restrict__ BH, const unsigned short* __restrict__ BL, int KPB,
               const float* __restrict__ bias, int N,
               float* __restrict__ C, int ldc, unsigned short* __restrict__ Op, int outPlane,
               int act, const float* __restrict__ prelu) {
    __shared__ __align__(16) unsigned short AsH[64 * 40];
    __shared__ __align__(16) unsigned short AsL[64 * 40];
    __shared__ __align__(16) unsigned short BsH[320 * 40];
    __shared__ __align__(16) unsigned short BsL[320 * 40];

    const int tid = threadIdx.x;
    const int bm = blockIdx.y * 64;
    const int bn = blockIdx.x * 320;
    const int wid = tid >> 6, lane = tid & 63;
    const int lr = lane & 15, lk = lane >> 4;
    const int ar = tid >> 2, ac = tid & 3;

    f32x4 acc[4][5];
#pragma unroll
    for (int m = 0; m < 4; ++m)
#pragma unroll
        for (int n = 0; n < 5; ++n) acc[m][n] = (f32x4)0.f;

    for (int k0 = 0; k0 < KP; k0 += 32) {
        {
            int gm = bm + ar;
            int k = k0 + ac * 8;
            float v[8];
#pragma unroll
            for (int j = 0; j < 8; ++j) v[j] = 0.f;
            if (gm < M) {
                if (k + 7 < K) {
                    float4 p0 = *(const float4*)&A[(size_t)gm * lda + k];
                    float4 p1 = *(const float4*)&A[(size_t)gm * lda + k + 4];
                    v[0] = p0.x; v[1] = p0.y; v[2] = p0.z; v[3] = p0.w;
                    v[4] = p1.x; v[5] = p1.y; v[6] = p1.z; v[7] = p1.w;
                } else {
#pragma unroll
                    for (int j = 0; j < 8; ++j)
                        if (k + j < K) v[j] = A[(size_t)gm * lda + k + j];
                }
            }
            us8 h, l;
#pragma unroll
            for (int j = 0; j < 8; ++j) {
                unsigned short hb = f2bf(v[j]);
                h[j] = hb;
                l[j] = f2bf(v[j] - bf2f(hb));
            }
            *(us8*)&AsH[ar * 40 + ac * 8] = h;
            *(us8*)&AsL[ar * 40 + ac * 8] = l;
        }
#pragma unroll
        for (int p = 0; p < 5; ++p) {
            int r = ar + p * 64;
            size_t gb = (size_t)(bn + r) * KPB + k0 + ac * 8;
            *(us8*)&BsH[r * 40 + ac * 8] = *(const us8*)&BH[gb];
            *(us8*)&BsL[r * 40 + ac * 8] = *(const us8*)&BL[gb];
        }
        __syncthreads();
        bf16x8 aH[4], aL[4];
#pragma unroll
        for (int m = 0; m < 4; ++m) {
            aH[m] = *(const bf16x8*)&AsH[(m * 16 + lr) * 40 + lk * 8];
            aL[m] = *(const bf16x8*)&AsL[(m * 16 + lr) * 40 + lk * 8];
        }
#pragma unroll
        for (int n = 0; n < 5; ++n) {
            int r = wid * 80 + n * 16 + lr;
            bf16x8 bh = *(const bf16x8*)&BsH[r * 40 + lk * 8];
            bf16x8 bl = *(const bf16x8*)&BsL[r * 40 + lk * 8];
#pragma unroll
            for (int m = 0; m < 4; ++m) {
                acc[m][n] = __builtin_amdgcn_mfma_f32_16x16x32_bf16(aH[m], bh, acc[m][n], 0, 0, 0);
                acc[m][n] = __builtin_amdgcn_mfma_f32_16x16x32_bf16(aH[m], bl, acc[m][n], 0, 0, 0);
                acc[m][n] = __builtin_amdgcn_mfma_f32_16x16x32_bf16(aL[m], bh, acc[m][n], 0, 0, 0);
            }
        }
        __syncthreads();
    }
    float slope = (act == 2) ? prelu[0] : 0.f;
#pragma unroll
    for (int n = 0; n < 5; ++n) {
        int col = bn + wid * 80 + n * 16 + lr;
        bool vc = col < N;
        float bv = vc ? bias[col] : 0.f;
#pragma unroll
        for (int m = 0; m < 4; ++m) {
            int rbase = bm + m * 16 + lk * 4;
#pragma unroll
            for (int q = 0; q < 4; ++q) {
                int row = rbase + q;
                if (row >= M) continue;
                float v = vc ? (acc[m][n][q] + bv) : 0.f;
                if (act == 1) v = fmaxf(v, 0.f);
                else if (act == 2) v = (v >= 0.f) ? v : slope * v;
                if (outPlane) {
                    if (col < PSTR) Op[(size_t)row * PSTR + col] = f2bf(v);
                } else if (vc) {
                    C[(size_t)row * ldc + col] = v;
                }
            }
        }
    }
}

// ---------------------------------------------------------------- segmented pool
__global__ __launch_bounds__(64)
void pool_seg(const unsigned short* __restrict__ h, const int* __restrict__ goffs,
              float* __restrict__ pooled) {
    int g = blockIdx.x;
    int lane = threadIdx.x;
    int s = goffs[g], e = goffs[g + 1];
    float a0 = 0.f, a1 = 0.f, a2 = 0.f, a3 = 0.f, a4 = 0.f, a5 = 0.f;
    for (int node = s; node < e; ++node) {
        const unsigned* r = (const unsigned*)(h + (size_t)node * PSTR);
        unsigned u0 = r[lane], u1 = r[64 + lane];
        a0 += bf2f((unsigned short)u0); a1 += bf2f((unsigned short)(u0 >> 16));
        a2 += bf2f((unsigned short)u1); a3 += bf2f((unsigned short)(u1 >> 16));
        if (lane < 22) {
            unsigned u2 = r[128 + lane];
            a4 += bf2f((unsigned short)u2); a5 += bf2f((unsigned short)(u2 >> 16));
        }
    }
    float* pr = pooled + (size_t)g * PSTR;
    *(float2*)&pr[2 * lane] = make_float2(a0, a1);
    *(float2*)&pr[128 + 2 * lane] = make_float2(a2, a3);
    if (lane < 24) {
        float2 t = (lane < 22) ? make_float2(a4, a5) : make_float2(0.f, 0.f);
        *(float2*)&pr[256 + 2 * lane] = t;
    }
}

// ---------------------------------------------------------------- launch
extern "C" void kernel_launch(void* const* d_in, const int* in_sizes, int n_in,
                              void* d_out, int out_size, void* d_ws, size_t ws_size,
                              hipStream_t stream) {
    const float* x      = (const float*)d_in[0];
    const int*   eidx   = (const int*)d_in[1];
    const int*   batch  = (const int*)d_in[2];
    const float* W_proj = (const float*)d_in[3];
    const float* b_proj = (const float*)d_in[4];
    const float* W1     = (const float*)d_in[5];
    const float* b1     = (const float*)d_in[6];
    const float* W2     = (const float*)d_in[7];
    const float* b2     = (const float*)d_in[8];
    const float* W_sp   = (const float*)d_in[9];
    const float* b_sp   = (const float*)d_in[10];
    const float* prelu  = (const float*)d_in[11];

    const int* src = eidx;
    const int* dst = eidx + N_EDGES;

    const size_t PLANE = (size_t)N_NODES * PSTR + 64;
    const int LAYER_SZ = 320 * 320;
    const int PROJ_SZ  = 320 * 128;
    const int SP_SZ    = 1280 * 320;
    const int NB  = (N_NODES + 255) / 256;
    const int NBG = (N_GRAPHS + 255) / 256;

    unsigned short* hplane = (unsigned short*)d_ws;
    unsigned short* aggp   = hplane + PLANE;
    unsigned short* tp     = aggp + PLANE;
    float* pooled = (float*)(tp + PLANE);
    unsigned short* projH = (unsigned short*)(pooled + (size_t)N_GRAPHS * PSTR + 16);
    unsigned short* projL = projH + PROJ_SZ;
    unsigned short* w1H   = projL + PROJ_SZ;
    unsigned short* w1L   = w1H + 5 * (size_t)LAYER_SZ;
    unsigned short* w2H   = w1L + 5 * (size_t)LAYER_SZ;
    unsigned short* w2L   = w2H + 5 * (size_t)LAYER_SZ;
    unsigned short* spH   = w2L + 5 * (size_t)LAYER_SZ;
    unsigned short* spL   = spH + SP_SZ;
    int* cnt    = (int*)(((uintptr_t)(spL + SP_SZ) + 15) & ~(uintptr_t)15);
    int* bsum   = cnt + N_NODES;
    int* bbase  = bsum + 256;
    int* offs   = bbase + 256;
    int* cursor = offs + N_NODES + 1;
    int* csr    = cursor + N_NODES;
    int* gcnt   = csr + N_EDGES;
    int* gsum   = gcnt + N_GRAPHS;
    int* gbase  = gsum + 256;
    int* goffs  = gbase + 256;
    int* gcur   = goffs + N_GRAPHS + 1;
    size_t needed = (size_t)((uintptr_t)(gcur + N_GRAPHS) - (uintptr_t)d_ws);
    if (ws_size < needed) return;

    // ---- weight pre-split ----
    split_weight_t<<<dim3(10, 4), 256, 0, stream>>>(W_proj, NODE_IN, HID, 128, projH, projL);
    for (int i = 0; i < DEPTH; ++i) {
        split_weight_t<<<dim3(10, 10), 256, 0, stream>>>(W1 + (size_t)i * HID * HID, HID, HID, 320,
                                                         w1H + (size_t)i * LAYER_SZ, w1L + (size_t)i * LAYER_SZ);
        split_weight_t<<<dim3(10, 10), 256, 0, stream>>>(W2 + (size_t)i * HID * HID, HID, HID, 320,
                                                         w2H + (size_t)i * LAYER_SZ, w2L + (size_t)i * LAYER_SZ);
    }
    split_weight_t<<<dim3(40, 10), 256, 0, stream>>>(W_sp, HID, READOUT, 320, spH, spL);

    // ---- CSR build (by dst) ----
    hipMemsetAsync(cnt, 0, N_NODES * sizeof(int), stream);
    hipMemsetAsync(gcnt, 0, N_GRAPHS * sizeof(int), stream);
    hist_kernel<<<(N_EDGES + 255) / 256, 256, 0, stream>>>(dst, cnt, N_EDGES);
    scan_block<<<NB, 256, 0, stream>>>(cnt, offs, bsum, N_NODES);
    scan_base<<<1, 256, 0, stream>>>(bsum, bbase, NB, offs + N_NODES);
    scan_add<<<NB, 256, 0, stream>>>(offs, bbase, cursor, N_NODES);
    scatter_kernel<<<(N_EDGES + 255) / 256, 256, 0, stream>>>(src, dst, cursor, csr, N_EDGES);

    // ---- graph offsets for pooling ----
    hist_kernel<<<(N_NODES + 255) / 256, 256, 0, stream>>>(batch, gcnt, N_NODES);
    scan_block<<<NBG, 256, 0, stream>>>(gcnt, goffs, gsum, N_GRAPHS);
    scan_base<<<1, 256, 0, stream>>>(gsum, gbase, NBG, goffs + N_GRAPHS);
    scan_add<<<NBG, 256, 0, stream>>>(goffs, gbase, gcur, N_GRAPHS);

    // ---- projection ----
    gemm_f32A<<<dim3(1, (N_NODES + 63) / 64), 256, 0, stream>>>(
        x, NODE_IN, N_NODES, NODE_IN, 128, projH, projL, 128,
        b_proj, HID, nullptr, 0, hplane, 1, 1, nullptr);

    // ---- GIN layers ----
    const int GB = (N_NODES + 63) / 64;
    for (int i = 0; i < DEPTH; ++i) {
        aggregate_bf16<<<(N_NODES * 64 + 255) / 256, 256, 0, stream>>>(hplane, offs, csr, aggp);
        gemm_plane2<<<GB, 256, 0, stream>>>(
            aggp, N_NODES, w1H + (size_t)i * LAYER_SZ, w1L + (size_t)i * LAYER_SZ,
            b1 + (size_t)i * HID, tp, 1);
        gemm_plane2<<<GB, 256, 0, stream>>>(
            tp, N_NODES, w2H + (size_t)i * LAYER_SZ, w2L + (size_t)i * LAYER_SZ,
            b2 + (size_t)i * HID, hplane, (i < DEPTH - 1) ? 1 : 0);
    }

    // ---- segmented pool ----
    pool_seg<<<N_GRAPHS, 64, 0, stream>>>(hplane, goffs, pooled);

    // ---- readout ----
    gemm_f32A<<<dim3(4, (N_GRAPHS + 63) / 64), 256, 0, stream>>>(
        pooled, PSTR, N_GRAPHS, HID, 320, spH, spL, 320,
        b_sp, READOUT, (float*)d_out, READOUT, nullptr, 0, 2, prelu);
}

// Round 6
// 1139.757 us; speedup vs baseline: 3.1201x; 1.1888x over previous
//
#include <hip/hip_runtime.h>
#include <cstdint>

#define N_NODES 50000
#define N_EDGES 800000
#define N_GRAPHS 1024
#define NODE_IN 128
#define HID 300
#define DEPTH 5
#define READOUT 1024
#define PSTR 304   // plane row stride (elements), 608B, 16B-aligned

typedef float f32x4 __attribute__((ext_vector_type(4)));
typedef short bf16x8 __attribute__((ext_vector_type(8)));
typedef unsigned short us8 __attribute__((ext_vector_type(8)));

__device__ inline unsigned short f2bf(float v) {
    unsigned u = __float_as_uint(v);
    unsigned r = u + 0x7FFFu + ((u >> 16) & 1u);
    return (unsigned short)(r >> 16);
}
__device__ inline float bf2f(unsigned short h) {
    return __uint_as_float((unsigned)h << 16);
}
__device__ inline float bflo(unsigned u) { return __uint_as_float(u << 16); }
__device__ inline float bfhi(unsigned u) { return __uint_as_float(u & 0xFFFF0000u); }
__device__ inline unsigned packbf(float a, float b) {
    return (unsigned)f2bf(a) | ((unsigned)f2bf(b) << 16);
}

// ---------------------------------------------------------------- CSR build
__global__ void hist_kernel(const int* __restrict__ dst, int* __restrict__ cnt, int n) {
    int i = blockIdx.x * blockDim.x + threadIdx.x;
    if (i < n) atomicAdd(&cnt[dst[i]], 1);
}

__global__ __launch_bounds__(256)
void scan_block(const int* __restrict__ in, int* __restrict__ out_excl,
                int* __restrict__ bsum, int n) {
    __shared__ int buf[256];
    int i = blockIdx.x * 256 + (int)threadIdx.x;
    int v = (i < n) ? in[i] : 0;
    buf[threadIdx.x] = v;
    __syncthreads();
    for (int off = 1; off < 256; off <<= 1) {
        int t = ((int)threadIdx.x >= off) ? buf[threadIdx.x - off] : 0;
        __syncthreads();
        buf[threadIdx.x] += t;
        __syncthreads();
    }
    if (i < n) out_excl[i] = buf[threadIdx.x] - v;
    if (threadIdx.x == 255) bsum[blockIdx.x] = buf[255];
}

__global__ __launch_bounds__(256)
void scan_base(const int* __restrict__ bsum, int* __restrict__ bbase, int nb,
               int* __restrict__ total) {
    __shared__ int buf[256];
    int v = ((int)threadIdx.x < nb) ? bsum[threadIdx.x] : 0;
    buf[threadIdx.x] = v;
    __syncthreads();
    for (int off = 1; off < 256; off <<= 1) {
        int t = ((int)threadIdx.x >= off) ? buf[threadIdx.x - off] : 0;
        __syncthreads();
        buf[threadIdx.x] += t;
        __syncthreads();
    }
    if ((int)threadIdx.x < nb) bbase[threadIdx.x] = buf[threadIdx.x] - v;
    if (threadIdx.x == 255) *total = buf[255];
}

__global__ void scan_add(int* __restrict__ offs, const int* __restrict__ bbase,
                         int* __restrict__ cursor, int n) {
    int i = blockIdx.x * blockDim.x + threadIdx.x;
    if (i < n) {
        int o = offs[i] + bbase[blockIdx.x];
        offs[i] = o;
        cursor[i] = o;
    }
}

__global__ void scatter_kernel(const int* __restrict__ src, const int* __restrict__ dst,
                               int* __restrict__ cursor, int* __restrict__ csr, int n) {
    int i = blockIdx.x * blockDim.x + threadIdx.x;
    if (i < n) {
        int p = atomicAdd(&cursor[dst[i]], 1);
        csr[p] = src[i];
    }
}

// ---------------------------------------------------------------- aggregation (bf16 planes)
// out[node] = h[node] + sum h[src]; uint2 (8B) main reads + dword tail, unroll-4 ILP
__global__ __launch_bounds__(256)
void aggregate_bf16(const unsigned short* __restrict__ h, const int* __restrict__ offs,
                    const int* __restrict__ csr, unsigned short* __restrict__ out) {
    int wave = (int)((blockIdx.x * blockDim.x + threadIdx.x) >> 6);
    int lane = threadIdx.x & 63;
    if (wave >= N_NODES) return;
    float a0, a1, a2, a3, a4, a5;
    {
        const unsigned* r = (const unsigned*)(h + (size_t)wave * PSTR);
        uint2 u = *(const uint2*)&r[2 * lane];
        unsigned t = (lane < 24) ? r[128 + lane] : 0u;
        a0 = bflo(u.x); a1 = bfhi(u.x);
        a2 = bflo(u.y); a3 = bfhi(u.y);
        a4 = bflo(t);   a5 = bfhi(t);
    }
    int s = offs[wave], e = offs[wave + 1];
    int k = s;
    for (; k + 3 < e; k += 4) {
        int i0 = csr[k], i1 = csr[k + 1], i2 = csr[k + 2], i3 = csr[k + 3];
        const unsigned* r0 = (const unsigned*)(h + (size_t)i0 * PSTR);
        const unsigned* r1 = (const unsigned*)(h + (size_t)i1 * PSTR);
        const unsigned* r2 = (const unsigned*)(h + (size_t)i2 * PSTR);
        const unsigned* r3 = (const unsigned*)(h + (size_t)i3 * PSTR);
        uint2 x0 = *(const uint2*)&r0[2 * lane];
        uint2 x1 = *(const uint2*)&r1[2 * lane];
        uint2 x2 = *(const uint2*)&r2[2 * lane];
        uint2 x3 = *(const uint2*)&r3[2 * lane];
        unsigned t0 = 0, t1 = 0, t2 = 0, t3 = 0;
        if (lane < 24) {
            t0 = r0[128 + lane]; t1 = r1[128 + lane];
            t2 = r2[128 + lane]; t3 = r3[128 + lane];
        }
        a0 += bflo(x0.x) + bflo(x1.x) + bflo(x2.x) + bflo(x3.x);
        a1 += bfhi(x0.x) + bfhi(x1.x) + bfhi(x2.x) + bfhi(x3.x);
        a2 += bflo(x0.y) + bflo(x1.y) + bflo(x2.y) + bflo(x3.y);
        a3 += bfhi(x0.y) + bfhi(x1.y) + bfhi(x2.y) + bfhi(x3.y);
        a4 += bflo(t0) + bflo(t1) + bflo(t2) + bflo(t3);
        a5 += bfhi(t0) + bfhi(t1) + bfhi(t2) + bfhi(t3);
    }
    for (; k < e; ++k) {
        const unsigned* r = (const unsigned*)(h + (size_t)csr[k] * PSTR);
        uint2 u = *(const uint2*)&r[2 * lane];
        unsigned t = (lane < 24) ? r[128 + lane] : 0u;
        a0 += bflo(u.x); a1 += bfhi(u.x);
        a2 += bflo(u.y); a3 += bfhi(u.y);
        a4 += bflo(t);   a5 += bfhi(t);
    }
    unsigned* o = (unsigned*)(out + (size_t)wave * PSTR);
    uint2 w; w.x = packbf(a0, a1); w.y = packbf(a2, a3);
    *(uint2*)&o[2 * lane] = w;
    if (lane < 24) o[128 + lane] = packbf(a4, a5);
}

// ---------------------------------------------------------------- weight pre-split (coalesced transpose)
__global__ __launch_bounds__(256)
void split_weight_t(const float* __restrict__ W, int K, int N, int KP,
                    unsigned short* __restrict__ H, unsigned short* __restrict__ L) {
    __shared__ float tile[32][33];
    int n0 = blockIdx.x * 32, k0 = blockIdx.y * 32;
    int tx = threadIdx.x & 31, ty = threadIdx.x >> 5;
#pragma unroll
    for (int r = 0; r < 4; ++r) {
        int k = k0 + ty + r * 8, n = n0 + tx;
        tile[ty + r * 8][tx] = (k < K && n < N) ? W[(size_t)k * N + n] : 0.f;
    }
    __syncthreads();
#pragma unroll
    for (int r = 0; r < 4; ++r) {
        int n = n0 + ty + r * 8, k = k0 + tx;
        float v = tile[tx][ty + r * 8];
        unsigned short hb = f2bf(v);
        H[(size_t)n * KP + k] = hb;
        L[(size_t)n * KP + k] = f2bf(v - bf2f(hb));
    }
}

// ---------------------------------------------------------------- hidden GEMM, big-M tile
// Out[M,300] = act( A(bf16 plane, K=320) @ (BH+BL)[320x320] + bias ) -> bf16 plane
// tile 256x320, BK=32, 512 thr = 8 waves (2M x 4N), wave tile 128x80 (8x5 frags)
// single round: 196 blocks. B LDS: 32-wide rows + XOR chunk swizzle. A LDS: pad-40.
#define BSWZ(r, c) ((c) ^ (((r) >> 1) & 3))
__global__ __launch_bounds__(512)
void gemm_plane3(const unsigned short* __restrict__ Ap, int M,
                 const unsigned short* __restrict__ BH, const unsigned short* __restrict__ BL,
                 const float* __restrict__ bias, unsigned short* __restrict__ Op, int act) {
    __shared__ __align__(16) unsigned short As[256 * 40];
    __shared__ __align__(16) unsigned short Bs[2 * 320 * 32];

    const int tid = threadIdx.x;
    const int bm = blockIdx.x * 256;
    const int wid = tid >> 6, lane = tid & 63;
    const int wm = wid >> 2, wn = wid & 3;
    const int lr = lane & 15, lk = lane >> 4;

    // A staging: thread -> row tid>>1, 2 consecutive b128 chunks
    const int arow = tid >> 1, ach = (tid & 1) * 2;
    int agr = bm + arow; if (agr >= M) agr = M - 1;
    const unsigned short* aSrc = Ap + (size_t)agr * PSTR + ach * 8;

    f32x4 acc[8][5];
#pragma unroll
    for (int m = 0; m < 8; ++m)
#pragma unroll
        for (int n = 0; n < 5; ++n) acc[m][n] = (f32x4)0.f;

    for (int t = 0; t < 10; ++t) {
        const int k0 = t * 32;
        // issue global loads BEFORE the barrier (overlap with other waves' compute)
        us8 vA0 = *(const us8*)&aSrc[k0];
        us8 vA1 = *(const us8*)&aSrc[k0 + 8];
        us8 vB[5];
        int br[5], bc[5], bp[5];
#pragma unroll
        for (int i = 0; i < 5; ++i) {
            int q = i * 512 + tid;
            int pl = q >= 1280;
            int q2 = q - (pl ? 1280 : 0);
            br[i] = q2 >> 2; bc[i] = q2 & 3; bp[i] = pl;
            const unsigned short* bsrc = pl ? BL : BH;
            vB[i] = *(const us8*)&bsrc[(size_t)br[i] * 320 + k0 + bc[i] * 8];
        }
        if (t) __syncthreads();
        *(us8*)&As[arow * 40 + ach * 8] = vA0;
        *(us8*)&As[arow * 40 + ach * 8 + 8] = vA1;
#pragma unroll
        for (int i = 0; i < 5; ++i)
            *(us8*)&Bs[bp[i] * 10240 + br[i] * 32 + BSWZ(br[i], bc[i]) * 8] = vB[i];
        __syncthreads();
        // compute: 80 MFMA per wave
        bf16x8 aS[8];
#pragma unroll
        for (int m = 0; m < 8; ++m)
            aS[m] = *(const bf16x8*)&As[(wm * 128 + m * 16 + lr) * 40 + lk * 8];
#pragma unroll
        for (int n = 0; n < 5; ++n) {
            int rb = wn * 80 + n * 16 + lr;
            int sc = rb * 32 + BSWZ(rb, lk) * 8;
            bf16x8 bh = *(const bf16x8*)&Bs[sc];
            bf16x8 bl = *(const bf16x8*)&Bs[10240 + sc];
#pragma unroll
            for (int m = 0; m < 8; ++m) {
                acc[m][n] = __builtin_amdgcn_mfma_f32_16x16x32_bf16(aS[m], bh, acc[m][n], 0, 0, 0);
                acc[m][n] = __builtin_amdgcn_mfma_f32_16x16x32_bf16(aS[m], bl, acc[m][n], 0, 0, 0);
            }
        }
    }
    // epilogue
#pragma unroll
    for (int n = 0; n < 5; ++n) {
        int col = wn * 80 + n * 16 + lr;
        bool vc = col < HID;
        float bv = vc ? bias[col] : 0.f;
#pragma unroll
        for (int m = 0; m < 8; ++m) {
            int rbase = bm + wm * 128 + m * 16 + lk * 4;
#pragma unroll
            for (int q = 0; q < 4; ++q) {
                int row = rbase + q;
                if (row >= M) continue;
                float v = vc ? (acc[m][n][q] + bv) : 0.f;
                if (act == 1) v = fmaxf(v, 0.f);
                if (col < PSTR) Op[(size_t)row * PSTR + col] = f2bf(v);
            }
        }
    }
}

// ---------------------------------------------------------------- GEMM: fp32 A (3-term split)
__global__ __launch_bounds__(256)
void gemm_f32A(const float* __restrict__ A, int lda, int M, int K, int KP,
               const unsigned short* __restrict__ BH, const unsigned short* __restrict__ BL, int KPB,
               const float* __restrict__ bias, int N,
               float* __restrict__ C, int ldc, unsigned short* __restrict__ Op, int outPlane,
               int act, const float* __restrict__ prelu) {
    __shared__ __align__(16) unsigned short AsH[64 * 40];
    __shared__ __align__(16) unsigned short AsL[64 * 40];
    __shared__ __align__(16) unsigned short BsH[320 * 40];
    __shared__ __align__(16) unsigned short BsL[320 * 40];

    const int tid = threadIdx.x;
    const int bm = blockIdx.y * 64;
    const int bn = blockIdx.x * 320;
    const int wid = tid >> 6, lane = tid & 63;
    const int lr = lane & 15, lk = lane >> 4;
    const int ar = tid >> 2, ac = tid & 3;

    f32x4 acc[4][5];
#pragma unroll
    for (int m = 0; m < 4; ++m)
#pragma unroll
        for (int n = 0; n < 5; ++n) acc[m][n] = (f32x4)0.f;

    for (int k0 = 0; k0 < KP; k0 += 32) {
        {
            int gm = bm + ar;
            int k = k0 + ac * 8;
            float v[8];
#pragma unroll
            for (int j = 0; j < 8; ++j) v[j] = 0.f;
            if (gm < M) {
                if (k + 7 < K) {
                    float4 p0 = *(const float4*)&A[(size_t)gm * lda + k];
                    float4 p1 = *(const float4*)&A[(size_t)gm * lda + k + 4];
                    v[0] = p0.x; v[1] = p0.y; v[2] = p0.z; v[3] = p0.w;
                    v[4] = p1.x; v[5] = p1.y; v[6] = p1.z; v[7] = p1.w;
                } else {
#pragma unroll
                    for (int j = 0; j < 8; ++j)
                        if (k + j < K) v[j] = A[(size_t)gm * lda + k + j];
                }
            }
            us8 h, l;
#pragma unroll
            for (int j = 0; j < 8; ++j) {
                unsigned short hb = f2bf(v[j]);
                h[j] = hb;
                l[j] = f2bf(v[j] - bf2f(hb));
            }
            *(us8*)&AsH[ar * 40 + ac * 8] = h;
            *(us8*)&AsL[ar * 40 + ac * 8] = l;
        }
#pragma unroll
        for (int p = 0; p < 5; ++p) {
            int r = ar + p * 64;
            size_t gb = (size_t)(bn + r) * KPB + k0 + ac * 8;
            *(us8*)&BsH[r * 40 + ac * 8] = *(const us8*)&BH[gb];
            *(us8*)&BsL[r * 40 + ac * 8] = *(const us8*)&BL[gb];
        }
        __syncthreads();
        bf16x8 aH[4], aL[4];
#pragma unroll
        for (int m = 0; m < 4; ++m) {
            aH[m] = *(const bf16x8*)&AsH[(m * 16 + lr) * 40 + lk * 8];
            aL[m] = *(const bf16x8*)&AsL[(m * 16 + lr) * 40 + lk * 8];
        }
#pragma unroll
        for (int n = 0; n < 5; ++n) {
            int r = wid * 80 + n * 16 + lr;
            bf16x8 bh = *(const bf16x8*)&BsH[r * 40 + lk * 8];
            bf16x8 bl = *(const bf16x8*)&BsL[r * 40 + lk * 8];
#pragma unroll
            for (int m = 0; m < 4; ++m) {
                acc[m][n] = __builtin_amdgcn_mfma_f32_16x16x32_bf16(aH[m], bh, acc[m][n], 0, 0, 0);
                acc[m][n] = __builtin_amdgcn_mfma_f32_16x16x32_bf16(aH[m], bl, acc[m][n], 0, 0, 0);
                acc[m][n] = __builtin_amdgcn_mfma_f32_16x16x32_bf16(aL[m], bh, acc[m][n], 0, 0, 0);
            }
        }
        __syncthreads();
    }
    float slope = (act == 2) ? prelu[0] : 0.f;
#pragma unroll
    for (int n = 0; n < 5; ++n) {
        int col = bn + wid * 80 + n * 16 + lr;
        bool vc = col < N;
        float bv = vc ? bias[col] : 0.f;
#pragma unroll
        for (int m = 0; m < 4; ++m) {
            int rbase = bm + m * 16 + lk * 4;
#pragma unroll
            for (int q = 0; q < 4; ++q) {
                int row = rbase + q;
                if (row >= M) continue;
                float v = vc ? (acc[m][n][q] + bv) : 0.f;
                if (act == 1) v = fmaxf(v, 0.f);
                else if (act == 2) v = (v >= 0.f) ? v : slope * v;
                if (outPlane) {
                    if (col < PSTR) Op[(size_t)row * PSTR + col] = f2bf(v);
                } else if (vc) {
                    C[(size_t)row * ldc + col] = v;
                }
            }
        }
    }
}

// ---------------------------------------------------------------- segmented pool
__global__ __launch_bounds__(64)
void pool_seg(const unsigned short* __restrict__ h, const int* __restrict__ goffs,
              float* __restrict__ pooled) {
    int g = blockIdx.x;
    int lane = threadIdx.x;
    int s = goffs[g], e = goffs[g + 1];
    float a0 = 0.f, a1 = 0.f, a2 = 0.f, a3 = 0.f, a4 = 0.f, a5 = 0.f;
    for (int node = s; node < e; ++node) {
        const unsigned* r = (const unsigned*)(h + (size_t)node * PSTR);
        uint2 u = *(const uint2*)&r[2 * lane];
        unsigned t = (lane < 24) ? r[128 + lane] : 0u;
        a0 += bflo(u.x); a1 += bfhi(u.x);
        a2 += bflo(u.y); a3 += bfhi(u.y);
        a4 += bflo(t);   a5 += bfhi(t);
    }
    float* pr = pooled + (size_t)g * PSTR;
    // elems 4*lane..4*lane+3 and 256+2*lane
    *(float4*)&pr[4 * lane] = make_float4(a0, a1, a2, a3);
    if (lane < 24) *(float2*)&pr[256 + 2 * lane] = make_float2(a4, a5);
}

// ---------------------------------------------------------------- launch
extern "C" void kernel_launch(void* const* d_in, const int* in_sizes, int n_in,
                              void* d_out, int out_size, void* d_ws, size_t ws_size,
                              hipStream_t stream) {
    const float* x      = (const float*)d_in[0];
    const int*   eidx   = (const int*)d_in[1];
    const int*   batch  = (const int*)d_in[2];
    const float* W_proj = (const float*)d_in[3];
    const float* b_proj = (const float*)d_in[4];
    const float* W1     = (const float*)d_in[5];
    const float* b1     = (const float*)d_in[6];
    const float* W2     = (const float*)d_in[7];
    const float* b2     = (const float*)d_in[8];
    const float* W_sp   = (const float*)d_in[9];
    const float* b_sp   = (const float*)d_in[10];
    const float* prelu  = (const float*)d_in[11];

    const int* src = eidx;
    const int* dst = eidx + N_EDGES;

    const size_t PLANE = (size_t)N_NODES * PSTR + 64;
    const int LAYER_SZ = 320 * 320;
    const int PROJ_SZ  = 320 * 128;
    const int SP_SZ    = 1280 * 320;
    const int NB  = (N_NODES + 255) / 256;
    const int NBG = (N_GRAPHS + 255) / 256;

    unsigned short* hplane = (unsigned short*)d_ws;
    unsigned short* aggp   = hplane + PLANE;
    unsigned short* tp     = aggp + PLANE;
    float* pooled = (float*)(tp + PLANE);
    unsigned short* projH = (unsigned short*)(pooled + (size_t)N_GRAPHS * PSTR + 16);
    unsigned short* projL = projH + PROJ_SZ;
    unsigned short* w1H   = projL + PROJ_SZ;
    unsigned short* w1L   = w1H + 5 * (size_t)LAYER_SZ;
    unsigned short* w2H   = w1L + 5 * (size_t)LAYER_SZ;
    unsigned short* w2L   = w2H + 5 * (size_t)LAYER_SZ;
    unsigned short* spH   = w2L + 5 * (size_t)LAYER_SZ;
    unsigned short* spL   = spH + SP_SZ;
    int* cnt    = (int*)(((uintptr_t)(spL + SP_SZ) + 15) & ~(uintptr_t)15);
    int* bsum   = cnt + N_NODES;
    int* bbase  = bsum + 256;
    int* offs   = bbase + 256;
    int* cursor = offs + N_NODES + 1;
    int* csr    = cursor + N_NODES;
    int* gcnt   = csr + N_EDGES;
    int* gsum   = gcnt + N_GRAPHS;
    int* gbase  = gsum + 256;
    int* goffs  = gbase + 256;
    int* gcur   = goffs + N_GRAPHS + 1;
    size_t needed = (size_t)((uintptr_t)(gcur + N_GRAPHS) - (uintptr_t)d_ws);
    if (ws_size < needed) return;

    // ---- weight pre-split ----
    split_weight_t<<<dim3(10, 4), 256, 0, stream>>>(W_proj, NODE_IN, HID, 128, projH, projL);
    for (int i = 0; i < DEPTH; ++i) {
        split_weight_t<<<dim3(10, 10), 256, 0, stream>>>(W1 + (size_t)i * HID * HID, HID, HID, 320,
                                                         w1H + (size_t)i * LAYER_SZ, w1L + (size_t)i * LAYER_SZ);
        split_weight_t<<<dim3(10, 10), 256, 0, stream>>>(W2 + (size_t)i * HID * HID, HID, HID, 320,
                                                         w2H + (size_t)i * LAYER_SZ, w2L + (size_t)i * LAYER_SZ);
    }
    split_weight_t<<<dim3(40, 10), 256, 0, stream>>>(W_sp, HID, READOUT, 320, spH, spL);

    // ---- CSR build (by dst) ----
    hipMemsetAsync(cnt, 0, N_NODES * sizeof(int), stream);
    hipMemsetAsync(gcnt, 0, N_GRAPHS * sizeof(int), stream);
    hist_kernel<<<(N_EDGES + 255) / 256, 256, 0, stream>>>(dst, cnt, N_EDGES);
    scan_block<<<NB, 256, 0, stream>>>(cnt, offs, bsum, N_NODES);
    scan_base<<<1, 256, 0, stream>>>(bsum, bbase, NB, offs + N_NODES);
    scan_add<<<NB, 256, 0, stream>>>(offs, bbase, cursor, N_NODES);
    scatter_kernel<<<(N_EDGES + 255) / 256, 256, 0, stream>>>(src, dst, cursor, csr, N_EDGES);

    // ---- graph offsets for pooling ----
    hist_kernel<<<(N_NODES + 255) / 256, 256, 0, stream>>>(batch, gcnt, N_NODES);
    scan_block<<<NBG, 256, 0, stream>>>(gcnt, goffs, gsum, N_GRAPHS);
    scan_base<<<1, 256, 0, stream>>>(gsum, gbase, NBG, goffs + N_GRAPHS);
    scan_add<<<NBG, 256, 0, stream>>>(goffs, gbase, gcur, N_GRAPHS);

    // ---- projection ----
    gemm_f32A<<<dim3(1, (N_NODES + 63) / 64), 256, 0, stream>>>(
        x, NODE_IN, N_NODES, NODE_IN, 128, projH, projL, 128,
        b_proj, HID, nullptr, 0, hplane, 1, 1, nullptr);

    // ---- GIN layers ----
    const int GB3 = (N_NODES + 255) / 256;   // 196 blocks, single round
    for (int i = 0; i < DEPTH; ++i) {
        aggregate_bf16<<<(N_NODES * 64 + 255) / 256, 256, 0, stream>>>(hplane, offs, csr, aggp);
        gemm_plane3<<<GB3, 512, 0, stream>>>(
            aggp, N_NODES, w1H + (size_t)i * LAYER_SZ, w1L + (size_t)i * LAYER_SZ,
            b1 + (size_t)i * HID, tp, 1);
        gemm_plane3<<<GB3, 512, 0, stream>>>(
            tp, N_NODES, w2H + (size_t)i * LAYER_SZ, w2L + (size_t)i * LAYER_SZ,
            b2 + (size_t)i * HID, hplane, (i < DEPTH - 1) ? 1 : 0);
    }

    // ---- segmented pool ----
    pool_seg<<<N_GRAPHS, 64, 0, stream>>>(hplane, goffs, pooled);

    // ---- readout ----
    gemm_f32A<<<dim3(4, (N_GRAPHS + 63) / 64), 256, 0, stream>>>(
        pooled, PSTR, N_GRAPHS, HID, 320, spH, spL, 320,
        b_sp, READOUT, (float*)d_out, READOUT, nullptr, 0, 2, prelu);
}

// Round 7
// 1138.445 us; speedup vs baseline: 3.1237x; 1.0012x over previous
//
#include <hip/hip_runtime.h>
#include <cstdint>

#define N_NODES 50000
#define N_EDGES 800000
#define N_GRAPHS 1024
#define NODE_IN 128
#define HID 300
#define DEPTH 5
#define READOUT 1024
#define PSTR 304   // plane row stride (elements), 608B, 16B-aligned
#define XSTR 384   // stacked proj plane stride = KP

typedef float f32x4 __attribute__((ext_vector_type(4)));
typedef short bf16x8 __attribute__((ext_vector_type(8)));
typedef unsigned short us8 __attribute__((ext_vector_type(8)));

__device__ inline unsigned short f2bf(float v) {
    unsigned u = __float_as_uint(v);
    unsigned r = u + 0x7FFFu + ((u >> 16) & 1u);
    return (unsigned short)(r >> 16);
}
__device__ inline float bf2f(unsigned short h) {
    return __uint_as_float((unsigned)h << 16);
}
__device__ inline float bflo(unsigned u) { return __uint_as_float(u << 16); }
__device__ inline float bfhi(unsigned u) { return __uint_as_float(u & 0xFFFF0000u); }
__device__ inline unsigned packbf(float a, float b) {
    return (unsigned)f2bf(a) | ((unsigned)f2bf(b) << 16);
}

// ---------------------------------------------------------------- CSR build
__global__ void hist_kernel(const int* __restrict__ dst, int* __restrict__ cnt, int n) {
    int i = blockIdx.x * blockDim.x + threadIdx.x;
    if (i < n) atomicAdd(&cnt[dst[i]], 1);
}

__global__ __launch_bounds__(256)
void scan_block(const int* __restrict__ in, int* __restrict__ out_excl,
                int* __restrict__ bsum, int n) {
    __shared__ int buf[256];
    int i = blockIdx.x * 256 + (int)threadIdx.x;
    int v = (i < n) ? in[i] : 0;
    buf[threadIdx.x] = v;
    __syncthreads();
    for (int off = 1; off < 256; off <<= 1) {
        int t = ((int)threadIdx.x >= off) ? buf[threadIdx.x - off] : 0;
        __syncthreads();
        buf[threadIdx.x] += t;
        __syncthreads();
    }
    if (i < n) out_excl[i] = buf[threadIdx.x] - v;
    if (threadIdx.x == 255) bsum[blockIdx.x] = buf[255];
}

__global__ __launch_bounds__(256)
void scan_base(const int* __restrict__ bsum, int* __restrict__ bbase, int nb,
               int* __restrict__ total) {
    __shared__ int buf[256];
    int v = ((int)threadIdx.x < nb) ? bsum[threadIdx.x] : 0;
    buf[threadIdx.x] = v;
    __syncthreads();
    for (int off = 1; off < 256; off <<= 1) {
        int t = ((int)threadIdx.x >= off) ? buf[threadIdx.x - off] : 0;
        __syncthreads();
        buf[threadIdx.x] += t;
        __syncthreads();
    }
    if ((int)threadIdx.x < nb) bbase[threadIdx.x] = buf[threadIdx.x] - v;
    if (threadIdx.x == 255) *total = buf[255];
}

__global__ void scan_add(int* __restrict__ offs, const int* __restrict__ bbase,
                         int* __restrict__ cursor, int n) {
    int i = blockIdx.x * blockDim.x + threadIdx.x;
    if (i < n) {
        int o = offs[i] + bbase[blockIdx.x];
        offs[i] = o;
        cursor[i] = o;
    }
}

__global__ void scatter_kernel(const int* __restrict__ src, const int* __restrict__ dst,
                               int* __restrict__ cursor, int* __restrict__ csr, int n) {
    int i = blockIdx.x * blockDim.x + threadIdx.x;
    if (i < n) {
        int p = atomicAdd(&cursor[dst[i]], 1);
        csr[p] = src[i];
    }
}

// ---------------------------------------------------------------- aggregation (bf16 planes)
// out[node] = h[node] + sum h[src]; unroll-8 for memory-level parallelism
__global__ __launch_bounds__(256)
void aggregate_bf16(const unsigned short* __restrict__ h, const int* __restrict__ offs,
                    const int* __restrict__ csr, unsigned short* __restrict__ out) {
    int wave = (int)((blockIdx.x * blockDim.x + threadIdx.x) >> 6);
    int lane = threadIdx.x & 63;
    if (wave >= N_NODES) return;
    float a0, a1, a2, a3, a4, a5;
    {
        const unsigned* r = (const unsigned*)(h + (size_t)wave * PSTR);
        uint2 u = *(const uint2*)&r[2 * lane];
        unsigned t = (lane < 24) ? r[128 + lane] : 0u;
        a0 = bflo(u.x); a1 = bfhi(u.x);
        a2 = bflo(u.y); a3 = bfhi(u.y);
        a4 = bflo(t);   a5 = bfhi(t);
    }
    int s = offs[wave], e = offs[wave + 1];
    int k = s;
    for (; k + 7 < e; k += 8) {
        const unsigned* rp[8];
#pragma unroll
        for (int i = 0; i < 8; ++i)
            rp[i] = (const unsigned*)(h + (size_t)csr[k + i] * PSTR);
        uint2 x[8];
        unsigned tl[8];
#pragma unroll
        for (int i = 0; i < 8; ++i) x[i] = *(const uint2*)&rp[i][2 * lane];
        if (lane < 24) {
#pragma unroll
            for (int i = 0; i < 8; ++i) tl[i] = rp[i][128 + lane];
        } else {
#pragma unroll
            for (int i = 0; i < 8; ++i) tl[i] = 0u;
        }
#pragma unroll
        for (int i = 0; i < 8; ++i) {
            a0 += bflo(x[i].x); a1 += bfhi(x[i].x);
            a2 += bflo(x[i].y); a3 += bfhi(x[i].y);
            a4 += bflo(tl[i]);  a5 += bfhi(tl[i]);
        }
    }
    for (; k < e; ++k) {
        const unsigned* r = (const unsigned*)(h + (size_t)csr[k] * PSTR);
        uint2 u = *(const uint2*)&r[2 * lane];
        unsigned t = (lane < 24) ? r[128 + lane] : 0u;
        a0 += bflo(u.x); a1 += bfhi(u.x);
        a2 += bflo(u.y); a3 += bfhi(u.y);
        a4 += bflo(t);   a5 += bfhi(t);
    }
    unsigned* o = (unsigned*)(out + (size_t)wave * PSTR);
    uint2 w; w.x = packbf(a0, a1); w.y = packbf(a2, a3);
    *(uint2*)&o[2 * lane] = w;
    if (lane < 24) o[128 + lane] = packbf(a4, a5);
}

// ---------------------------------------------------------------- weight pre-split (coalesced transpose)
__global__ __launch_bounds__(256)
void split_weight_t(const float* __restrict__ W, int K, int N, int KP,
                    unsigned short* __restrict__ H, unsigned short* __restrict__ L) {
    __shared__ float tile[32][33];
    int n0 = blockIdx.x * 32, k0 = blockIdx.y * 32;
    int tx = threadIdx.x & 31, ty = threadIdx.x >> 5;
#pragma unroll
    for (int r = 0; r < 4; ++r) {
        int k = k0 + ty + r * 8, n = n0 + tx;
        tile[ty + r * 8][tx] = (k < K && n < N) ? W[(size_t)k * N + n] : 0.f;
    }
    __syncthreads();
#pragma unroll
    for (int r = 0; r < 4; ++r) {
        int n = n0 + ty + r * 8, k = k0 + tx;
        float v = tile[tx][ty + r * 8];
        unsigned short hb = f2bf(v);
        H[(size_t)n * KP + k] = hb;
        L[(size_t)n * KP + k] = f2bf(v - bf2f(hb));
    }
}

// W_proj [128][300] -> Bp [320][384]: rows n; cols: [Whi | Whi | Wlo] (transposed)
__global__ __launch_bounds__(256)
void split_wproj(const float* __restrict__ W, unsigned short* __restrict__ Bp) {
    __shared__ float tile[32][33];
    int n0 = blockIdx.x * 32, k0 = blockIdx.y * 32;
    int tx = threadIdx.x & 31, ty = threadIdx.x >> 5;
#pragma unroll
    for (int r = 0; r < 4; ++r) {
        int k = k0 + ty + r * 8, n = n0 + tx;
        tile[ty + r * 8][tx] = (k < NODE_IN && n < HID) ? W[(size_t)k * HID + n] : 0.f;
    }
    __syncthreads();
#pragma unroll
    for (int r = 0; r < 4; ++r) {
        int n = n0 + ty + r * 8, k = k0 + tx;
        float v = tile[tx][ty + r * 8];
        unsigned short hb = f2bf(v);
        unsigned short lb = f2bf(v - bf2f(hb));
        Bp[(size_t)n * XSTR + k] = hb;
        Bp[(size_t)n * XSTR + 128 + k] = hb;
        Bp[(size_t)n * XSTR + 256 + k] = lb;
    }
}

// x [50000][128] fp32 -> xs plane [50000][384] bf16 = [xh | xl | xh]
__global__ void split_x(const float* __restrict__ x, unsigned short* __restrict__ xs) {
    int i = blockIdx.x * blockDim.x + threadIdx.x;  // one per 2 floats
    if (i >= N_NODES * 64) return;
    int row = i >> 6, c = i & 63;
    float2 v = *(const float2*)&x[(size_t)row * NODE_IN + 2 * c];
    unsigned short h0 = f2bf(v.x), h1 = f2bf(v.y);
    unsigned short l0 = f2bf(v.x - bf2f(h0)), l1 = f2bf(v.y - bf2f(h1));
    unsigned hp = (unsigned)h0 | ((unsigned)h1 << 16);
    unsigned lp = (unsigned)l0 | ((unsigned)l1 << 16);
    unsigned* o = (unsigned*)(xs + (size_t)row * XSTR);
    o[c] = hp;
    o[64 + c] = lp;
    o[128 + c] = hp;
}

// ---------------------------------------------------------------- plane GEMM, double-buffered
// Out[M,300] = act( A(bf16 plane, stride astr, K=KP) @ B-planes[320xKP] + bias ) -> bf16 plane
// tile 256x320, BK=32, 512 thr = 8 waves (2M x 4N), wave tile 128x80.
// NPL=2: B = BH+BL (2 MFMA/frag). NPL=1: B = BH only (stacked-K trick for projection).
#define BSWZ(r, c) ((c) ^ (((r) >> 1) & 3))
template<int NPL>
__global__ __launch_bounds__(512)
void gemm_plane4(const unsigned short* __restrict__ Ap, int astr, int M, int KP,
                 const unsigned short* __restrict__ BH, const unsigned short* __restrict__ BL,
                 const float* __restrict__ bias, unsigned short* __restrict__ Op, int act) {
    constexpr int BITER = (NPL * 1280 + 511) / 512;
    __shared__ __align__(16) unsigned short As[2][256 * 40];
    __shared__ __align__(16) unsigned short Bs[2][NPL * 10240];

    const int tid = threadIdx.x;
    const int bm = blockIdx.x * 256;
    const int wid = tid >> 6, lane = tid & 63;
    const int wm = wid >> 2, wn = wid & 3;
    const int lr = lane & 15, lk = lane >> 4;
    const int arow = tid >> 1, ach = (tid & 1) * 2;
    int agr = bm + arow; if (agr >= M) agr = M - 1;
    const unsigned short* aSrc = Ap + (size_t)agr * astr + ach * 8;

    // per-thread B chunk meta (k-invariant)
    const unsigned short* bsrc[BITER];
    int bldso[BITER];
    bool bval[BITER];
#pragma unroll
    for (int i = 0; i < BITER; ++i) {
        int q = i * 512 + tid;
        bval[i] = q < NPL * 1280;
        int p = (NPL == 2 && q >= 1280) ? 1 : 0;
        int q2 = q - p * 1280;
        int r = q2 >> 2, c = q2 & 3;
        const unsigned short* base = p ? BL : BH;
        bsrc[i] = base + (size_t)r * KP + c * 8;
        bldso[i] = p * 10240 + r * 32 + BSWZ(r, c) * 8;
    }

    f32x4 acc[8][5];
#pragma unroll
    for (int m = 0; m < 8; ++m)
#pragma unroll
        for (int n = 0; n < 5; ++n) acc[m][n] = (f32x4)0.f;

    us8 vA0, vA1, vB[BITER];
    auto LOADS = [&](int t) {
        int k0 = t * 32;
        vA0 = *(const us8*)&aSrc[k0];
        vA1 = *(const us8*)&aSrc[k0 + 8];
#pragma unroll
        for (int i = 0; i < BITER; ++i)
            if (bval[i]) vB[i] = *(const us8*)&bsrc[i][k0];
    };
    auto WRITE = [&](int b) {
        *(us8*)&As[b][arow * 40 + ach * 8] = vA0;
        *(us8*)&As[b][arow * 40 + ach * 8 + 8] = vA1;
#pragma unroll
        for (int i = 0; i < BITER; ++i)
            if (bval[i]) *(us8*)&Bs[b][bldso[i]] = vB[i];
    };

    const int nt = KP / 32;
    LOADS(0);
    WRITE(0);
    int buf = 0;
    for (int t = 0; t < nt; ++t) {
        bool more = (t + 1 < nt);
        if (more) LOADS(t + 1);          // in flight across the barrier
        __syncthreads();                  // LDS[buf] complete; prev compute drained
        bf16x8 aS[8];
#pragma unroll
        for (int m = 0; m < 8; ++m)
            aS[m] = *(const bf16x8*)&As[buf][(wm * 128 + m * 16 + lr) * 40 + lk * 8];
#pragma unroll
        for (int n = 0; n < 5; ++n) {
            int rb = wn * 80 + n * 16 + lr;
            int sc = rb * 32 + BSWZ(rb, lk) * 8;
            bf16x8 bh = *(const bf16x8*)&Bs[buf][sc];
#pragma unroll
            for (int m = 0; m < 8; ++m)
                acc[m][n] = __builtin_amdgcn_mfma_f32_16x16x32_bf16(aS[m], bh, acc[m][n], 0, 0, 0);
            if (NPL == 2) {
                bf16x8 bl = *(const bf16x8*)&Bs[buf][10240 + sc];
#pragma unroll
                for (int m = 0; m < 8; ++m)
                    acc[m][n] = __builtin_amdgcn_mfma_f32_16x16x32_bf16(aS[m], bl, acc[m][n], 0, 0, 0);
            }
        }
        if (more) WRITE(buf ^ 1);        // waits vmcnt after compute; latency hidden
        buf ^= 1;
    }
    // epilogue
#pragma unroll
    for (int n = 0; n < 5; ++n) {
        int col = wn * 80 + n * 16 + lr;
        bool vc = col < HID;
        float bv = vc ? bias[col] : 0.f;
#pragma unroll
        for (int m = 0; m < 8; ++m) {
            int rbase = bm + wm * 128 + m * 16 + lk * 4;
#pragma unroll
            for (int q = 0; q < 4; ++q) {
                int row = rbase + q;
                if (row >= M) continue;
                float v = vc ? (acc[m][n][q] + bv) : 0.f;
                if (act == 1) v = fmaxf(v, 0.f);
                if (col < PSTR) Op[(size_t)row * PSTR + col] = f2bf(v);
            }
        }
    }
}

// ---------------------------------------------------------------- GEMM: fp32 A (readout only)
__global__ __launch_bounds__(256)
void gemm_f32A(const float* __restrict__ A, int lda, int M, int K, int KP,
               const unsigned short* __restrict__ BH, const unsigned short* __restrict__ BL, int KPB,
               const float* __restrict__ bias, int N,
               float* __restrict__ C, int ldc, int act, const float* __restrict__ prelu) {
    __shared__ __align__(16) unsigned short AsH[64 * 40];
    __shared__ __align__(16) unsigned short AsL[64 * 40];
    __shared__ __align__(16) unsigned short BsH[320 * 40];
    __shared__ __align__(16) unsigned short BsL[320 * 40];

    const int tid = threadIdx.x;
    const int bm = blockIdx.y * 64;
    const int bn = blockIdx.x * 320;
    const int wid = tid >> 6, lane = tid & 63;
    const int lr = lane & 15, lk = lane >> 4;
    const int ar = tid >> 2, ac = tid & 3;

    f32x4 acc[4][5];
#pragma unroll
    for (int m = 0; m < 4; ++m)
#pragma unroll
        for (int n = 0; n < 5; ++n) acc[m][n] = (f32x4)0.f;

    for (int k0 = 0; k0 < KP; k0 += 32) {
        {
            int gm = bm + ar;
            int k = k0 + ac * 8;
            float v[8];
#pragma unroll
            for (int j = 0; j < 8; ++j) v[j] = 0.f;
            if (gm < M) {
                if (k + 7 < K) {
                    float4 p0 = *(const float4*)&A[(size_t)gm * lda + k];
                    float4 p1 = *(const float4*)&A[(size_t)gm * lda + k + 4];
                    v[0] = p0.x; v[1] = p0.y; v[2] = p0.z; v[3] = p0.w;
                    v[4] = p1.x; v[5] = p1.y; v[6] = p1.z; v[7] = p1.w;
                } else {
#pragma unroll
                    for (int j = 0; j < 8; ++j)
                        if (k + j < K) v[j] = A[(size_t)gm * lda + k + j];
                }
            }
            us8 h, l;
#pragma unroll
            for (int j = 0; j < 8; ++j) {
                unsigned short hb = f2bf(v[j]);
                h[j] = hb;
                l[j] = f2bf(v[j] - bf2f(hb));
            }
            *(us8*)&AsH[ar * 40 + ac * 8] = h;
            *(us8*)&AsL[ar * 40 + ac * 8] = l;
        }
#pragma unroll
        for (int p = 0; p < 5; ++p) {
            int r = ar + p * 64;
            size_t gb = (size_t)(bn + r) * KPB + k0 + ac * 8;
            *(us8*)&BsH[r * 40 + ac * 8] = *(const us8*)&BH[gb];
            *(us8*)&BsL[r * 40 + ac * 8] = *(const us8*)&BL[gb];
        }
        __syncthreads();
        bf16x8 aH[4], aL[4];
#pragma unroll
        for (int m = 0; m < 4; ++m) {
            aH[m] = *(const bf16x8*)&AsH[(m * 16 + lr) * 40 + lk * 8];
            aL[m] = *(const bf16x8*)&AsL[(m * 16 + lr) * 40 + lk * 8];
        }
#pragma unroll
        for (int n = 0; n < 5; ++n) {
            int r = wid * 80 + n * 16 + lr;
            bf16x8 bh = *(const bf16x8*)&BsH[r * 40 + lk * 8];
            bf16x8 bl = *(const bf16x8*)&BsL[r * 40 + lk * 8];
#pragma unroll
            for (int m = 0; m < 4; ++m) {
                acc[m][n] = __builtin_amdgcn_mfma_f32_16x16x32_bf16(aH[m], bh, acc[m][n], 0, 0, 0);
                acc[m][n] = __builtin_amdgcn_mfma_f32_16x16x32_bf16(aH[m], bl, acc[m][n], 0, 0, 0);
                acc[m][n] = __builtin_amdgcn_mfma_f32_16x16x32_bf16(aL[m], bh, acc[m][n], 0, 0, 0);
            }
        }
        __syncthreads();
    }
    float slope = (act == 2) ? prelu[0] : 0.f;
#pragma unroll
    for (int n = 0; n < 5; ++n) {
        int col = bn + wid * 80 + n * 16 + lr;
        bool vc = col < N;
        float bv = vc ? bias[col] : 0.f;
#pragma unroll
        for (int m = 0; m < 4; ++m) {
            int rbase = bm + m * 16 + lk * 4;
#pragma unroll
            for (int q = 0; q < 4; ++q) {
                int row = rbase + q;
                if (row >= M) continue;
                float v = vc ? (acc[m][n][q] + bv) : 0.f;
                if (act == 1) v = fmaxf(v, 0.f);
                else if (act == 2) v = (v >= 0.f) ? v : slope * v;
                if (vc) C[(size_t)row * ldc + col] = v;
            }
        }
    }
}

// ---------------------------------------------------------------- segmented pool
__global__ __launch_bounds__(64)
void pool_seg(const unsigned short* __restrict__ h, const int* __restrict__ goffs,
              float* __restrict__ pooled) {
    int g = blockIdx.x;
    int lane = threadIdx.x;
    int s = goffs[g], e = goffs[g + 1];
    float a0 = 0.f, a1 = 0.f, a2 = 0.f, a3 = 0.f, a4 = 0.f, a5 = 0.f;
    for (int node = s; node < e; ++node) {
        const unsigned* r = (const unsigned*)(h + (size_t)node * PSTR);
        uint2 u = *(const uint2*)&r[2 * lane];
        unsigned t = (lane < 24) ? r[128 + lane] : 0u;
        a0 += bflo(u.x); a1 += bfhi(u.x);
        a2 += bflo(u.y); a3 += bfhi(u.y);
        a4 += bflo(t);   a5 += bfhi(t);
    }
    float* pr = pooled + (size_t)g * PSTR;
    *(float4*)&pr[4 * lane] = make_float4(a0, a1, a2, a3);
    if (lane < 24) *(float2*)&pr[256 + 2 * lane] = make_float2(a4, a5);
}

// ---------------------------------------------------------------- launch
extern "C" void kernel_launch(void* const* d_in, const int* in_sizes, int n_in,
                              void* d_out, int out_size, void* d_ws, size_t ws_size,
                              hipStream_t stream) {
    const float* x      = (const float*)d_in[0];
    const int*   eidx   = (const int*)d_in[1];
    const int*   batch  = (const int*)d_in[2];
    const float* W_proj = (const float*)d_in[3];
    const float* b_proj = (const float*)d_in[4];
    const float* W1     = (const float*)d_in[5];
    const float* b1     = (const float*)d_in[6];
    const float* W2     = (const float*)d_in[7];
    const float* b2     = (const float*)d_in[8];
    const float* W_sp   = (const float*)d_in[9];
    const float* b_sp   = (const float*)d_in[10];
    const float* prelu  = (const float*)d_in[11];

    const int* src = eidx;
    const int* dst = eidx + N_EDGES;

    const size_t PLANE = (size_t)N_NODES * PSTR + 64;
    const int LAYER_SZ = 320 * 320;
    const int SP_SZ    = 1280 * 320;
    const int BP_SZ    = 320 * XSTR;
    const int NB  = (N_NODES + 255) / 256;
    const int NBG = (N_GRAPHS + 255) / 256;

    unsigned short* hplane = (unsigned short*)d_ws;
    unsigned short* aggp   = hplane + PLANE;
    unsigned short* tp     = aggp + PLANE;
    unsigned short* xs     = aggp;                 // overlay: dead during projection
    float* pooled = (float*)(tp + PLANE);
    unsigned short* w1H   = (unsigned short*)(pooled + (size_t)N_GRAPHS * PSTR + 16);
    unsigned short* w1L   = w1H + 5 * (size_t)LAYER_SZ;
    unsigned short* w2H   = w1L + 5 * (size_t)LAYER_SZ;
    unsigned short* w2L   = w2H + 5 * (size_t)LAYER_SZ;
    unsigned short* spH   = w2L + 5 * (size_t)LAYER_SZ;
    unsigned short* spL   = spH + SP_SZ;
    unsigned short* Bp    = spL + SP_SZ;
    int* cnt    = (int*)(((uintptr_t)(Bp + BP_SZ) + 15) & ~(uintptr_t)15);
    int* bsum   = cnt + N_NODES;
    int* bbase  = bsum + 256;
    int* offs   = bbase + 256;
    int* cursor = offs + N_NODES + 1;
    int* csr    = cursor + N_NODES;
    int* gcnt   = csr + N_EDGES;
    int* gsum   = gcnt + N_GRAPHS;
    int* gbase  = gsum + 256;
    int* goffs  = gbase + 256;
    int* gcur   = goffs + N_GRAPHS + 1;
    size_t needed = (size_t)((uintptr_t)(gcur + N_GRAPHS) - (uintptr_t)d_ws);
    if (ws_size < needed) return;

    // ---- weight pre-split ----
    split_wproj<<<dim3(10, 4), 256, 0, stream>>>(W_proj, Bp);
    for (int i = 0; i < DEPTH; ++i) {
        split_weight_t<<<dim3(10, 10), 256, 0, stream>>>(W1 + (size_t)i * HID * HID, HID, HID, 320,
                                                         w1H + (size_t)i * LAYER_SZ, w1L + (size_t)i * LAYER_SZ);
        split_weight_t<<<dim3(10, 10), 256, 0, stream>>>(W2 + (size_t)i * HID * HID, HID, HID, 320,
                                                         w2H + (size_t)i * LAYER_SZ, w2L + (size_t)i * LAYER_SZ);
    }
    split_weight_t<<<dim3(40, 10), 256, 0, stream>>>(W_sp, HID, READOUT, 320, spH, spL);

    // ---- input split (into aggp/tp overlay) ----
    split_x<<<(N_NODES * 64 + 255) / 256, 256, 0, stream>>>(x, xs);

    // ---- CSR build (by dst) ----
    hipMemsetAsync(cnt, 0, N_NODES * sizeof(int), stream);
    hipMemsetAsync(gcnt, 0, N_GRAPHS * sizeof(int), stream);
    hist_kernel<<<(N_EDGES + 255) / 256, 256, 0, stream>>>(dst, cnt, N_EDGES);
    scan_block<<<NB, 256, 0, stream>>>(cnt, offs, bsum, N_NODES);
    scan_base<<<1, 256, 0, stream>>>(bsum, bbase, NB, offs + N_NODES);
    scan_add<<<NB, 256, 0, stream>>>(offs, bbase, cursor, N_NODES);
    scatter_kernel<<<(N_EDGES + 255) / 256, 256, 0, stream>>>(src, dst, cursor, csr, N_EDGES);

    // ---- graph offsets for pooling ----
    hist_kernel<<<(N_NODES + 255) / 256, 256, 0, stream>>>(batch, gcnt, N_NODES);
    scan_block<<<NBG, 256, 0, stream>>>(gcnt, goffs, gsum, N_GRAPHS);
    scan_base<<<1, 256, 0, stream>>>(gsum, gbase, NBG, goffs + N_GRAPHS);
    scan_add<<<NBG, 256, 0, stream>>>(goffs, gbase, gcur, N_GRAPHS);

    const int GB = (N_NODES + 255) / 256;   // 196 blocks

    // ---- projection: h0 = relu([xh|xl|xh] @ [Whi;Whi;Wlo] + b) ----
    gemm_plane4<1><<<GB, 512, 0, stream>>>(xs, XSTR, N_NODES, XSTR,
                                           Bp, nullptr, b_proj, hplane, 1);

    // ---- GIN layers ----
    for (int i = 0; i < DEPTH; ++i) {
        aggregate_bf16<<<(N_NODES * 64 + 255) / 256, 256, 0, stream>>>(hplane, offs, csr, aggp);
        gemm_plane4<2><<<GB, 512, 0, stream>>>(
            aggp, PSTR, N_NODES, 320,
            w1H + (size_t)i * LAYER_SZ, w1L + (size_t)i * LAYER_SZ,
            b1 + (size_t)i * HID, tp, 1);
        gemm_plane4<2><<<GB, 512, 0, stream>>>(
            tp, PSTR, N_NODES, 320,
            w2H + (size_t)i * LAYER_SZ, w2L + (size_t)i * LAYER_SZ,
            b2 + (size_t)i * HID, hplane, (i < DEPTH - 1) ? 1 : 0);
    }

    // ---- segmented pool ----
    pool_seg<<<N_GRAPHS, 64, 0, stream>>>(hplane, goffs, pooled);

    // ---- readout ----
    gemm_f32A<<<dim3(4, (N_GRAPHS + 63) / 64), 256, 0, stream>>>(
        pooled, PSTR, N_GRAPHS, HID, 320, spH, spL, 320,
        b_sp, READOUT, (float*)d_out, READOUT, 2, prelu);
}

// Round 8
// 980.513 us; speedup vs baseline: 3.6268x; 1.1611x over previous
//
#include <hip/hip_runtime.h>
#include <cstdint>

#define N_NODES 50000
#define N_EDGES 800000
#define N_GRAPHS 1024
#define NODE_IN 128
#define HID 300
#define DEPTH 5
#define READOUT 1024
#define PSTR 320   // plane row stride (elements): 640B, 128B-aligned rows
#define XSTR 384   // stacked proj plane stride

typedef float f32x4 __attribute__((ext_vector_type(4)));
typedef short bf16x8 __attribute__((ext_vector_type(8)));
typedef unsigned short us8 __attribute__((ext_vector_type(8)));

__device__ inline unsigned short f2bf(float v) {
    unsigned u = __float_as_uint(v);
    unsigned r = u + 0x7FFFu + ((u >> 16) & 1u);
    return (unsigned short)(r >> 16);
}
__device__ inline float bf2f(unsigned short h) {
    return __uint_as_float((unsigned)h << 16);
}
__device__ inline float bflo(unsigned u) { return __uint_as_float(u << 16); }
__device__ inline float bfhi(unsigned u) { return __uint_as_float(u & 0xFFFF0000u); }
__device__ inline unsigned packbf(float a, float b) {
    return (unsigned)f2bf(a) | ((unsigned)f2bf(b) << 16);
}

// ---------------------------------------------------------------- CSR build
__global__ void hist_kernel(const int* __restrict__ dst, int* __restrict__ cnt, int n) {
    int i = blockIdx.x * blockDim.x + threadIdx.x;
    if (i < n) atomicAdd(&cnt[dst[i]], 1);
}

__global__ __launch_bounds__(256)
void scan_block(const int* __restrict__ in, int* __restrict__ out_excl,
                int* __restrict__ bsum, int n) {
    __shared__ int buf[256];
    int i = blockIdx.x * 256 + (int)threadIdx.x;
    int v = (i < n) ? in[i] : 0;
    buf[threadIdx.x] = v;
    __syncthreads();
    for (int off = 1; off < 256; off <<= 1) {
        int t = ((int)threadIdx.x >= off) ? buf[threadIdx.x - off] : 0;
        __syncthreads();
        buf[threadIdx.x] += t;
        __syncthreads();
    }
    if (i < n) out_excl[i] = buf[threadIdx.x] - v;
    if (threadIdx.x == 255) bsum[blockIdx.x] = buf[255];
}

__global__ __launch_bounds__(256)
void scan_base(const int* __restrict__ bsum, int* __restrict__ bbase, int nb,
               int* __restrict__ total) {
    __shared__ int buf[256];
    int v = ((int)threadIdx.x < nb) ? bsum[threadIdx.x] : 0;
    buf[threadIdx.x] = v;
    __syncthreads();
    for (int off = 1; off < 256; off <<= 1) {
        int t = ((int)threadIdx.x >= off) ? buf[threadIdx.x - off] : 0;
        __syncthreads();
        buf[threadIdx.x] += t;
        __syncthreads();
    }
    if ((int)threadIdx.x < nb) bbase[threadIdx.x] = buf[threadIdx.x] - v;
    if (threadIdx.x == 255) *total = buf[255];
}

__global__ void scan_add(int* __restrict__ offs, const int* __restrict__ bbase,
                         int* __restrict__ cursor, int n) {
    int i = blockIdx.x * blockDim.x + threadIdx.x;
    if (i < n) {
        int o = offs[i] + bbase[blockIdx.x];
        offs[i] = o;
        cursor[i] = o;
    }
}

__global__ void scatter_kernel(const int* __restrict__ src, const int* __restrict__ dst,
                               int* __restrict__ cursor, int* __restrict__ csr, int n) {
    int i = blockIdx.x * blockDim.x + threadIdx.x;
    if (i < n) {
        int p = atomicAdd(&cursor[dst[i]], 1);
        csr[p] = src[i];
    }
}

// ---------------------------------------------------------------- aggregation (bf16 planes)
// out[node] = h[node] + sum h[src]; rows 640B aligned; unroll-4 (best measured)
__global__ __launch_bounds__(256)
void aggregate_bf16(const unsigned short* __restrict__ h, const int* __restrict__ offs,
                    const int* __restrict__ csr, unsigned short* __restrict__ out) {
    int wave = (int)((blockIdx.x * blockDim.x + threadIdx.x) >> 6);
    int lane = threadIdx.x & 63;
    if (wave >= N_NODES) return;
    float a0, a1, a2, a3, a4, a5;
    {
        const unsigned* r = (const unsigned*)(h + (size_t)wave * PSTR);
        uint2 u = *(const uint2*)&r[2 * lane];
        unsigned t = (lane < 32) ? r[128 + lane] : 0u;
        a0 = bflo(u.x); a1 = bfhi(u.x);
        a2 = bflo(u.y); a3 = bfhi(u.y);
        a4 = bflo(t);   a5 = bfhi(t);
    }
    int s = offs[wave], e = offs[wave + 1];
    int k = s;
    for (; k + 3 < e; k += 4) {
        const unsigned* r0 = (const unsigned*)(h + (size_t)csr[k] * PSTR);
        const unsigned* r1 = (const unsigned*)(h + (size_t)csr[k + 1] * PSTR);
        const unsigned* r2 = (const unsigned*)(h + (size_t)csr[k + 2] * PSTR);
        const unsigned* r3 = (const unsigned*)(h + (size_t)csr[k + 3] * PSTR);
        uint2 x0 = *(const uint2*)&r0[2 * lane];
        uint2 x1 = *(const uint2*)&r1[2 * lane];
        uint2 x2 = *(const uint2*)&r2[2 * lane];
        uint2 x3 = *(const uint2*)&r3[2 * lane];
        unsigned t0 = 0, t1 = 0, t2 = 0, t3 = 0;
        if (lane < 32) {
            t0 = r0[128 + lane]; t1 = r1[128 + lane];
            t2 = r2[128 + lane]; t3 = r3[128 + lane];
        }
        a0 += bflo(x0.x) + bflo(x1.x) + bflo(x2.x) + bflo(x3.x);
        a1 += bfhi(x0.x) + bfhi(x1.x) + bfhi(x2.x) + bfhi(x3.x);
        a2 += bflo(x0.y) + bflo(x1.y) + bflo(x2.y) + bflo(x3.y);
        a3 += bfhi(x0.y) + bfhi(x1.y) + bfhi(x2.y) + bfhi(x3.y);
        a4 += bflo(t0) + bflo(t1) + bflo(t2) + bflo(t3);
        a5 += bfhi(t0) + bfhi(t1) + bfhi(t2) + bfhi(t3);
    }
    for (; k < e; ++k) {
        const unsigned* r = (const unsigned*)(h + (size_t)csr[k] * PSTR);
        uint2 u = *(const uint2*)&r[2 * lane];
        unsigned t = (lane < 32) ? r[128 + lane] : 0u;
        a0 += bflo(u.x); a1 += bfhi(u.x);
        a2 += bflo(u.y); a3 += bfhi(u.y);
        a4 += bflo(t);   a5 += bfhi(t);
    }
    unsigned* o = (unsigned*)(out + (size_t)wave * PSTR);
    uint2 w; w.x = packbf(a0, a1); w.y = packbf(a2, a3);
    *(uint2*)&o[2 * lane] = w;
    if (lane < 32) o[128 + lane] = (lane < 22) ? packbf(a4, a5) : 0u;
}

// ---------------------------------------------------------------- weight pre-split (coalesced transpose)
__global__ __launch_bounds__(256)
void split_weight_t(const float* __restrict__ W, int K, int N, int KP,
                    unsigned short* __restrict__ H, unsigned short* __restrict__ L) {
    __shared__ float tile[32][33];
    int n0 = blockIdx.x * 32, k0 = blockIdx.y * 32;
    int tx = threadIdx.x & 31, ty = threadIdx.x >> 5;
#pragma unroll
    for (int r = 0; r < 4; ++r) {
        int k = k0 + ty + r * 8, n = n0 + tx;
        tile[ty + r * 8][tx] = (k < K && n < N) ? W[(size_t)k * N + n] : 0.f;
    }
    __syncthreads();
#pragma unroll
    for (int r = 0; r < 4; ++r) {
        int n = n0 + ty + r * 8, k = k0 + tx;
        float v = tile[tx][ty + r * 8];
        unsigned short hb = f2bf(v);
        H[(size_t)n * KP + k] = hb;
        L[(size_t)n * KP + k] = f2bf(v - bf2f(hb));
    }
}

// W_proj [128][300] -> Bp [320][384]: [Whi | Whi | Wlo] transposed
__global__ __launch_bounds__(256)
void split_wproj(const float* __restrict__ W, unsigned short* __restrict__ Bp) {
    __shared__ float tile[32][33];
    int n0 = blockIdx.x * 32, k0 = blockIdx.y * 32;
    int tx = threadIdx.x & 31, ty = threadIdx.x >> 5;
#pragma unroll
    for (int r = 0; r < 4; ++r) {
        int k = k0 + ty + r * 8, n = n0 + tx;
        tile[ty + r * 8][tx] = (k < NODE_IN && n < HID) ? W[(size_t)k * HID + n] : 0.f;
    }
    __syncthreads();
#pragma unroll
    for (int r = 0; r < 4; ++r) {
        int n = n0 + ty + r * 8, k = k0 + tx;
        float v = tile[tx][ty + r * 8];
        unsigned short hb = f2bf(v);
        unsigned short lb = f2bf(v - bf2f(hb));
        Bp[(size_t)n * XSTR + k] = hb;
        Bp[(size_t)n * XSTR + 128 + k] = hb;
        Bp[(size_t)n * XSTR + 256 + k] = lb;
    }
}

// x -> xs plane [50000][384] = [xh | xl | xh]
__global__ void split_x(const float* __restrict__ x, unsigned short* __restrict__ xs) {
    int i = blockIdx.x * blockDim.x + threadIdx.x;
    if (i >= N_NODES * 64) return;
    int row = i >> 6, c = i & 63;
    float2 v = *(const float2*)&x[(size_t)row * NODE_IN + 2 * c];
    unsigned short h0 = f2bf(v.x), h1 = f2bf(v.y);
    unsigned short l0 = f2bf(v.x - bf2f(h0)), l1 = f2bf(v.y - bf2f(h1));
    unsigned hp = (unsigned)h0 | ((unsigned)h1 << 16);
    unsigned lp = (unsigned)l0 | ((unsigned)l1 << 16);
    unsigned* o = (unsigned*)(xs + (size_t)row * XSTR);
    o[c] = hp;
    o[64 + c] = lp;
    o[128 + c] = hp;
}

// ---------------------------------------------------------------- fused GIN MLP layer
// out = act2( relu( agg@ (W1H+W1L) + b1 ) @ (W2H+W2L) + b2 )  -> bf16 plane
// 391 blocks x 128 rows, 512 thr (8 waves, 2M x 4N, wave tile 64x80).
// LDS: At (A then T then Out staging, 80KB, XOR-swizzled) + Bs (40KB single-buf) = 120KB.
#define BSWZ(r, c) ((c) ^ (((r) >> 1) & 3))
__global__ __launch_bounds__(512)
void gin_mlp(const unsigned short* __restrict__ Ap, int M,
             const unsigned short* __restrict__ B1H, const unsigned short* __restrict__ B1L,
             const float* __restrict__ b1,
             const unsigned short* __restrict__ B2H, const unsigned short* __restrict__ B2L,
             const float* __restrict__ b2,
             unsigned short* __restrict__ Op, int act2) {
    __shared__ __align__(16) unsigned short At[128 * 320];   // 80 KB
    __shared__ __align__(16) unsigned short Bs[2 * 10240];   // 40 KB (hi|lo halves)

    const int tid = threadIdx.x;
    const int bm = blockIdx.x * 128;
    const int wid = tid >> 6, lane = tid & 63;
    const int wm = wid >> 2, wn = wid & 3;
    const int lr = lane & 15, lk = lane >> 4;

    // bias per output col (5 frags)
    float b1v[5], b2v[5];
#pragma unroll
    for (int n = 0; n < 5; ++n) {
        int col = wn * 80 + n * 16 + lr;
        b1v[n] = (col < HID) ? b1[col] : 0.f;
        b2v[n] = (col < HID) ? b2[col] : 0.f;
    }

    // ---- stage A (128 x 320, once) ----
#pragma unroll
    for (int i = 0; i < 10; ++i) {
        int g = i * 512 + tid;        // 0..5119
        int row = g / 40, c = g - row * 40;
        int grow = bm + row; if (grow >= M) grow = M - 1;
        us8 v = *(const us8*)&Ap[(size_t)grow * PSTR + c * 8];
        *(us8*)&At[row * 320 + (c ^ (row & 7)) * 8] = v;
    }

    // B chunk meta (shared by both GEMMs)
    const int q = tid;                          // 512 thr x 5 iters cover 2560 chunks
    size_t bofs[5]; int bldso[5]; bool bpl[5];
#pragma unroll
    for (int i = 0; i < 5; ++i) {
        int qq = i * 512 + q;
        bool pl = qq >= 1280;
        int q2 = qq - (pl ? 1280 : 0);
        int r = q2 >> 2, c = q2 & 3;
        bpl[i] = pl;
        bofs[i] = (size_t)r * 320 + c * 8;
        bldso[i] = (pl ? 10240 : 0) + r * 32 + BSWZ(r, c) * 8;
    }

    f32x4 acc[4][5];
    us8 vB[5];

    auto LOADB = [&](const unsigned short* BH, const unsigned short* BL, int t) {
        int k0 = t * 32;
#pragma unroll
        for (int i = 0; i < 5; ++i) {
            const unsigned short* base = bpl[i] ? BL : BH;
            vB[i] = *(const us8*)&base[bofs[i] + k0];
        }
    };
    auto RUN = [&](const unsigned short* BH, const unsigned short* BL) {
        for (int t = 0; t < 10; ++t) {
            __syncthreads();                     // Bs free / At & Bs visible
#pragma unroll
            for (int i = 0; i < 5; ++i) *(us8*)&Bs[bldso[i]] = vB[i];
            if (t < 9) LOADB(BH, BL, t + 1);     // in flight under compute
            __syncthreads();                     // Bs ready
            bf16x8 aS[4];
#pragma unroll
            for (int m = 0; m < 4; ++m) {
                int row = wm * 64 + m * 16 + lr;
                int c = t * 4 + lk;
                aS[m] = *(const bf16x8*)&At[row * 320 + (c ^ (row & 7)) * 8];
            }
#pragma unroll
            for (int n = 0; n < 5; ++n) {
                int rb = wn * 80 + n * 16 + lr;
                int sc = rb * 32 + BSWZ(rb, lk) * 8;
                bf16x8 bh = *(const bf16x8*)&Bs[sc];
                bf16x8 bl = *(const bf16x8*)&Bs[10240 + sc];
#pragma unroll
                for (int m = 0; m < 4; ++m) {
                    acc[m][n] = __builtin_amdgcn_mfma_f32_16x16x32_bf16(aS[m], bh, acc[m][n], 0, 0, 0);
                    acc[m][n] = __builtin_amdgcn_mfma_f32_16x16x32_bf16(aS[m], bl, acc[m][n], 0, 0, 0);
                }
            }
        }
    };

    // ---- GEMM1 ----
#pragma unroll
    for (int m = 0; m < 4; ++m)
#pragma unroll
        for (int n = 0; n < 5; ++n) acc[m][n] = (f32x4)0.f;
    LOADB(B1H, B1L, 0);
    RUN(B1H, B1L);

    // prefetch GEMM2's first B tile during the T phase
    LOADB(B2H, B2L, 0);

    // ---- T = relu(acc + b1) -> At (overwrite; pads col>=HID set 0) ----
    __syncthreads();                             // all waves done reading At/Bs
#pragma unroll
    for (int n = 0; n < 5; ++n) {
        int col = wn * 80 + n * 16 + lr;
        int cc = col >> 3, cp = col & 7;
        float bv = b1v[n];
        bool vc = col < HID;
#pragma unroll
        for (int m = 0; m < 4; ++m) {
#pragma unroll
            for (int p = 0; p < 4; ++p) {
                int row = wm * 64 + m * 16 + lk * 4 + p;
                float v = vc ? fmaxf(acc[m][n][p] + bv, 0.f) : 0.f;
                At[row * 320 + ((cc ^ (row & 7)) * 8) + cp] = f2bf(v);
            }
        }
    }

    // ---- GEMM2 (first __syncthreads in RUN covers T visibility) ----
#pragma unroll
    for (int m = 0; m < 4; ++m)
#pragma unroll
        for (int n = 0; n < 5; ++n) acc[m][n] = (f32x4)0.f;
    RUN(B2H, B2L);

    // ---- epilogue: act2(acc + b2) -> At -> coalesced global stores ----
    __syncthreads();
#pragma unroll
    for (int n = 0; n < 5; ++n) {
        int col = wn * 80 + n * 16 + lr;
        int cc = col >> 3, cp = col & 7;
        float bv = b2v[n];
        bool vc = col < HID;
#pragma unroll
        for (int m = 0; m < 4; ++m) {
#pragma unroll
            for (int p = 0; p < 4; ++p) {
                int row = wm * 64 + m * 16 + lk * 4 + p;
                float v = vc ? (acc[m][n][p] + bv) : 0.f;
                if (act2) v = fmaxf(v, 0.f);
                At[row * 320 + ((cc ^ (row & 7)) * 8) + cp] = f2bf(v);
            }
        }
    }
    __syncthreads();
#pragma unroll
    for (int i = 0; i < 10; ++i) {
        int g = i * 512 + tid;
        int row = g / 40, c = g - row * 40;
        int grow = bm + row;
        if (grow < M)
            *(us8*)&Op[(size_t)grow * PSTR + c * 8] =
                *(const us8*)&At[row * 320 + (c ^ (row & 7)) * 8];
    }
}

// ---------------------------------------------------------------- projection GEMM (dbuf, plane out)
template<int NPL>
__global__ __launch_bounds__(512)
void gemm_plane4(const unsigned short* __restrict__ Ap, int astr, int M, int KP,
                 const unsigned short* __restrict__ BH, const unsigned short* __restrict__ BL,
                 const float* __restrict__ bias, unsigned short* __restrict__ Op, int act) {
    constexpr int BITER = (NPL * 1280 + 511) / 512;
    __shared__ __align__(16) unsigned short As[2][256 * 40];
    __shared__ __align__(16) unsigned short Bs[2][NPL * 10240];

    const int tid = threadIdx.x;
    const int bm = blockIdx.x * 256;
    const int wid = tid >> 6, lane = tid & 63;
    const int wm = wid >> 2, wn = wid & 3;
    const int lr = lane & 15, lk = lane >> 4;
    const int arow = tid >> 1, ach = (tid & 1) * 2;
    int agr = bm + arow; if (agr >= M) agr = M - 1;
    const unsigned short* aSrc = Ap + (size_t)agr * astr + ach * 8;

    const unsigned short* bsrc[BITER];
    int bldso[BITER];
    bool bval[BITER];
#pragma unroll
    for (int i = 0; i < BITER; ++i) {
        int qq = i * 512 + tid;
        bval[i] = qq < NPL * 1280;
        int p = (NPL == 2 && qq >= 1280) ? 1 : 0;
        int q2 = qq - p * 1280;
        int r = q2 >> 2, c = q2 & 3;
        const unsigned short* base = p ? BL : BH;
        bsrc[i] = base + (size_t)r * KP + c * 8;
        bldso[i] = p * 10240 + r * 32 + BSWZ(r, c) * 8;
    }

    f32x4 acc[8][5];
#pragma unroll
    for (int m = 0; m < 8; ++m)
#pragma unroll
        for (int n = 0; n < 5; ++n) acc[m][n] = (f32x4)0.f;

    us8 vA0, vA1, vB[BITER];
    auto LOADS = [&](int t) {
        int k0 = t * 32;
        vA0 = *(const us8*)&aSrc[k0];
        vA1 = *(const us8*)&aSrc[k0 + 8];
#pragma unroll
        for (int i = 0; i < BITER; ++i)
            if (bval[i]) vB[i] = *(const us8*)&bsrc[i][k0];
    };
    auto WRITE = [&](int b) {
        *(us8*)&As[b][arow * 40 + ach * 8] = vA0;
        *(us8*)&As[b][arow * 40 + ach * 8 + 8] = vA1;
#pragma unroll
        for (int i = 0; i < BITER; ++i)
            if (bval[i]) *(us8*)&Bs[b][bldso[i]] = vB[i];
    };

    const int nt = KP / 32;
    LOADS(0);
    WRITE(0);
    int buf = 0;
    for (int t = 0; t < nt; ++t) {
        bool more = (t + 1 < nt);
        if (more) LOADS(t + 1);
        __syncthreads();
        bf16x8 aS[8];
#pragma unroll
        for (int m = 0; m < 8; ++m)
            aS[m] = *(const bf16x8*)&As[buf][(wm * 128 + m * 16 + lr) * 40 + lk * 8];
#pragma unroll
        for (int n = 0; n < 5; ++n) {
            int rb = wn * 80 + n * 16 + lr;
            int sc = rb * 32 + BSWZ(rb, lk) * 8;
            bf16x8 bh = *(const bf16x8*)&Bs[buf][sc];
#pragma unroll
            for (int m = 0; m < 8; ++m)
                acc[m][n] = __builtin_amdgcn_mfma_f32_16x16x32_bf16(aS[m], bh, acc[m][n], 0, 0, 0);
            if (NPL == 2) {
                bf16x8 bl = *(const bf16x8*)&Bs[buf][10240 + sc];
#pragma unroll
                for (int m = 0; m < 8; ++m)
                    acc[m][n] = __builtin_amdgcn_mfma_f32_16x16x32_bf16(aS[m], bl, acc[m][n], 0, 0, 0);
            }
        }
        if (more) WRITE(buf ^ 1);
        buf ^= 1;
    }
#pragma unroll
    for (int n = 0; n < 5; ++n) {
        int col = wn * 80 + n * 16 + lr;
        bool vc = col < HID;
        float bv = vc ? bias[col] : 0.f;
#pragma unroll
        for (int m = 0; m < 8; ++m) {
            int rbase = bm + wm * 128 + m * 16 + lk * 4;
#pragma unroll
            for (int p = 0; p < 4; ++p) {
                int row = rbase + p;
                if (row >= M) continue;
                float v = vc ? (acc[m][n][p] + bv) : 0.f;
                if (act == 1) v = fmaxf(v, 0.f);
                Op[(size_t)row * PSTR + col] = f2bf(v);
            }
        }
    }
}

// ---------------------------------------------------------------- GEMM: fp32 A (readout only)
__global__ __launch_bounds__(256)
void gemm_f32A(const float* __restrict__ A, int lda, int M, int K, int KP,
               const unsigned short* __restrict__ BH, const unsigned short* __restrict__ BL, int KPB,
               const float* __restrict__ bias, int N,
               float* __restrict__ C, int ldc, int act, const float* __restrict__ prelu) {
    __shared__ __align__(16) unsigned short AsH[64 * 40];
    __shared__ __align__(16) unsigned short AsL[64 * 40];
    __shared__ __align__(16) unsigned short BsH[320 * 40];
    __shared__ __align__(16) unsigned short BsL[320 * 40];

    const int tid = threadIdx.x;
    const int bm = blockIdx.y * 64;
    const int bn = blockIdx.x * 320;
    const int wid = tid >> 6, lane = tid & 63;
    const int lr = lane & 15, lk = lane >> 4;
    const int ar = tid >> 2, ac = tid & 3;

    f32x4 acc[4][5];
#pragma unroll
    for (int m = 0; m < 4; ++m)
#pragma unroll
        for (int n = 0; n < 5; ++n) acc[m][n] = (f32x4)0.f;

    for (int k0 = 0; k0 < KP; k0 += 32) {
        {
            int gm = bm + ar;
            int k = k0 + ac * 8;
            float v[8];
#pragma unroll
            for (int j = 0; j < 8; ++j) v[j] = 0.f;
            if (gm < M) {
                if (k + 7 < K) {
                    float4 p0 = *(const float4*)&A[(size_t)gm * lda + k];
                    float4 p1 = *(const float4*)&A[(size_t)gm * lda + k + 4];
                    v[0] = p0.x; v[1] = p0.y; v[2] = p0.z; v[3] = p0.w;
                    v[4] = p1.x; v[5] = p1.y; v[6] = p1.z; v[7] = p1.w;
                } else {
#pragma unroll
                    for (int j = 0; j < 8; ++j)
                        if (k + j < K) v[j] = A[(size_t)gm * lda + k + j];
                }
            }
            us8 h, l;
#pragma unroll
            for (int j = 0; j < 8; ++j) {
                unsigned short hb = f2bf(v[j]);
                h[j] = hb;
                l[j] = f2bf(v[j] - bf2f(hb));
            }
            *(us8*)&AsH[ar * 40 + ac * 8] = h;
            *(us8*)&AsL[ar * 40 + ac * 8] = l;
        }
#pragma unroll
        for (int p = 0; p < 5; ++p) {
            int r = ar + p * 64;
            size_t gb = (size_t)(bn + r) * KPB + k0 + ac * 8;
            *(us8*)&BsH[r * 40 + ac * 8] = *(const us8*)&BH[gb];
            *(us8*)&BsL[r * 40 + ac * 8] = *(const us8*)&BL[gb];
        }
        __syncthreads();
        bf16x8 aH[4], aL[4];
#pragma unroll
        for (int m = 0; m < 4; ++m) {
            aH[m] = *(const bf16x8*)&AsH[(m * 16 + lr) * 40 + lk * 8];
            aL[m] = *(const bf16x8*)&AsL[(m * 16 + lr) * 40 + lk * 8];
        }
#pragma unroll
        for (int n = 0; n < 5; ++n) {
            int r = wid * 80 + n * 16 + lr;
            bf16x8 bh = *(const bf16x8*)&BsH[r * 40 + lk * 8];
            bf16x8 bl = *(const bf16x8*)&BsL[r * 40 + lk * 8];
#pragma unroll
            for (int m = 0; m < 4; ++m) {
                acc[m][n] = __builtin_amdgcn_mfma_f32_16x16x32_bf16(aH[m], bh, acc[m][n], 0, 0, 0);
                acc[m][n] = __builtin_amdgcn_mfma_f32_16x16x32_bf16(aH[m], bl, acc[m][n], 0, 0, 0);
                acc[m][n] = __builtin_amdgcn_mfma_f32_16x16x32_bf16(aL[m], bh, acc[m][n], 0, 0, 0);
            }
        }
        __syncthreads();
    }
    float slope = (act == 2) ? prelu[0] : 0.f;
#pragma unroll
    for (int n = 0; n < 5; ++n) {
        int col = bn + wid * 80 + n * 16 + lr;
        bool vc = col < N;
        float bv = vc ? bias[col] : 0.f;
#pragma unroll
        for (int m = 0; m < 4; ++m) {
            int rbase = bm + m * 16 + lk * 4;
#pragma unroll
            for (int p = 0; p < 4; ++p) {
                int row = rbase + p;
                if (row >= M) continue;
                float v = vc ? (acc[m][n][p] + bv) : 0.f;
                if (act == 1) v = fmaxf(v, 0.f);
                else if (act == 2) v = (v >= 0.f) ? v : slope * v;
                if (vc) C[(size_t)row * ldc + col] = v;
            }
        }
    }
}

// ---------------------------------------------------------------- segmented pool
__global__ __launch_bounds__(64)
void pool_seg(const unsigned short* __restrict__ h, const int* __restrict__ goffs,
              float* __restrict__ pooled) {
    int g = blockIdx.x;
    int lane = threadIdx.x;
    int s = goffs[g], e = goffs[g + 1];
    float a0 = 0.f, a1 = 0.f, a2 = 0.f, a3 = 0.f, a4 = 0.f, a5 = 0.f;
    for (int node = s; node < e; ++node) {
        const unsigned* r = (const unsigned*)(h + (size_t)node * PSTR);
        uint2 u = *(const uint2*)&r[2 * lane];
        unsigned t = (lane < 32) ? r[128 + lane] : 0u;
        a0 += bflo(u.x); a1 += bfhi(u.x);
        a2 += bflo(u.y); a3 += bfhi(u.y);
        a4 += bflo(t);   a5 += bfhi(t);
    }
    float* pr = pooled + (size_t)g * PSTR;
    *(float4*)&pr[4 * lane] = make_float4(a0, a1, a2, a3);
    if (lane < 32) *(float2*)&pr[256 + 2 * lane] = make_float2(a4, a5);
}

// ---------------------------------------------------------------- launch
extern "C" void kernel_launch(void* const* d_in, const int* in_sizes, int n_in,
                              void* d_out, int out_size, void* d_ws, size_t ws_size,
                              hipStream_t stream) {
    const float* x      = (const float*)d_in[0];
    const int*   eidx   = (const int*)d_in[1];
    const int*   batch  = (const int*)d_in[2];
    const float* W_proj = (const float*)d_in[3];
    const float* b_proj = (const float*)d_in[4];
    const float* W1     = (const float*)d_in[5];
    const float* b1     = (const float*)d_in[6];
    const float* W2     = (const float*)d_in[7];
    const float* b2     = (const float*)d_in[8];
    const float* W_sp   = (const float*)d_in[9];
    const float* b_sp   = (const float*)d_in[10];
    const float* prelu  = (const float*)d_in[11];

    const int* src = eidx;
    const int* dst = eidx + N_EDGES;

    const size_t PLANE  = (size_t)N_NODES * PSTR + 64;
    const size_t XPLANE = (size_t)N_NODES * XSTR + 64;   // xs overlay needs more than PLANE
    const int LAYER_SZ = 320 * 320;
    const int SP_SZ    = 1280 * 320;
    const int BP_SZ    = 320 * XSTR;
    const int NB  = (N_NODES + 255) / 256;
    const int NBG = (N_GRAPHS + 255) / 256;

    unsigned short* hplane = (unsigned short*)d_ws;
    unsigned short* aggp   = hplane + PLANE;       // also xs overlay (XPLANE-sized slot)
    unsigned short* xs     = aggp;
    float* pooled = (float*)(aggp + XPLANE);
    unsigned short* w1H   = (unsigned short*)(pooled + (size_t)N_GRAPHS * PSTR + 16);
    unsigned short* w1L   = w1H + 5 * (size_t)LAYER_SZ;
    unsigned short* w2H   = w1L + 5 * (size_t)LAYER_SZ;
    unsigned short* w2L   = w2H + 5 * (size_t)LAYER_SZ;
    unsigned short* spH   = w2L + 5 * (size_t)LAYER_SZ;
    unsigned short* spL   = spH + SP_SZ;
    unsigned short* Bp    = spL + SP_SZ;
    int* cnt    = (int*)(((uintptr_t)(Bp + BP_SZ) + 15) & ~(uintptr_t)15);
    int* bsum   = cnt + N_NODES;
    int* bbase  = bsum + 256;
    int* offs   = bbase + 256;
    int* cursor = offs + N_NODES + 1;
    int* csr    = cursor + N_NODES;
    int* gcnt   = csr + N_EDGES;
    int* gsum   = gcnt + N_GRAPHS;
    int* gbase  = gsum + 256;
    int* goffs  = gbase + 256;
    int* gcur   = goffs + N_GRAPHS + 1;
    size_t needed = (size_t)((uintptr_t)(gcur + N_GRAPHS) - (uintptr_t)d_ws);
    if (ws_size < needed) return;

    // ---- weight pre-split ----
    split_wproj<<<dim3(10, 4), 256, 0, stream>>>(W_proj, Bp);
    for (int i = 0; i < DEPTH; ++i) {
        split_weight_t<<<dim3(10, 10), 256, 0, stream>>>(W1 + (size_t)i * HID * HID, HID, HID, 320,
                                                         w1H + (size_t)i * LAYER_SZ, w1L + (size_t)i * LAYER_SZ);
        split_weight_t<<<dim3(10, 10), 256, 0, stream>>>(W2 + (size_t)i * HID * HID, HID, HID, 320,
                                                         w2H + (size_t)i * LAYER_SZ, w2L + (size_t)i * LAYER_SZ);
    }
    split_weight_t<<<dim3(40, 10), 256, 0, stream>>>(W_sp, HID, READOUT, 320, spH, spL);

    // ---- input split (xs overlays aggp slot; dead before first aggregate) ----
    split_x<<<(N_NODES * 64 + 255) / 256, 256, 0, stream>>>(x, xs);

    // ---- CSR build (by dst) ----
    hipMemsetAsync(cnt, 0, N_NODES * sizeof(int), stream);
    hipMemsetAsync(gcnt, 0, N_GRAPHS * sizeof(int), stream);
    hist_kernel<<<(N_EDGES + 255) / 256, 256, 0, stream>>>(dst, cnt, N_EDGES);
    scan_block<<<NB, 256, 0, stream>>>(cnt, offs, bsum, N_NODES);
    scan_base<<<1, 256, 0, stream>>>(bsum, bbase, NB, offs + N_NODES);
    scan_add<<<NB, 256, 0, stream>>>(offs, bbase, cursor, N_NODES);
    scatter_kernel<<<(N_EDGES + 255) / 256, 256, 0, stream>>>(src, dst, cursor, csr, N_EDGES);

    // ---- graph offsets for pooling ----
    hist_kernel<<<(N_NODES + 255) / 256, 256, 0, stream>>>(batch, gcnt, N_NODES);
    scan_block<<<NBG, 256, 0, stream>>>(gcnt, goffs, gsum, N_GRAPHS);
    scan_base<<<1, 256, 0, stream>>>(gsum, gbase, NBG, goffs + N_GRAPHS);
    scan_add<<<NBG, 256, 0, stream>>>(goffs, gbase, gcur, N_GRAPHS);

    // ---- projection: h0 = relu([xh|xl|xh] @ [Whi;Whi;Wlo] + b) -> hplane ----
    gemm_plane4<1><<<(N_NODES + 255) / 256, 512, 0, stream>>>(
        xs, XSTR, N_NODES, XSTR, Bp, nullptr, b_proj, hplane, 1);

    // ---- GIN layers: agg (h->aggp) + fused MLP (aggp->h) ----
    const int GBM = (N_NODES + 127) / 128;   // 391
    for (int i = 0; i < DEPTH; ++i) {
        aggregate_bf16<<<(N_NODES * 64 + 255) / 256, 256, 0, stream>>>(hplane, offs, csr, aggp);
        gin_mlp<<<GBM, 512, 0, stream>>>(
            aggp, N_NODES,
            w1H + (size_t)i * LAYER_SZ, w1L + (size_t)i * LAYER_SZ, b1 + (size_t)i * HID,
            w2H + (size_t)i * LAYER_SZ, w2L + (size_t)i * LAYER_SZ, b2 + (size_t)i * HID,
            hplane, (i < DEPTH - 1) ? 1 : 0);
    }

    // ---- segmented pool ----
    pool_seg<<<N_GRAPHS, 64, 0, stream>>>(hplane, goffs, pooled);

    // ---- readout ----
    gemm_f32A<<<dim3(4, (N_GRAPHS + 63) / 64), 256, 0, stream>>>(
        pooled, PSTR, N_GRAPHS, HID, 320, spH, spL, 320,
        b_sp, READOUT, (float*)d_out, READOUT, 2, prelu);
}